// Round 8
// baseline (149.356 us; speedup 1.0000x reference)
//
#include <hip/hip_runtime.h>
#include <hip/hip_bf16.h>

#define BB 4
#define SS 1024
#define DDIM 1024
#define HH 16
#define MROWS (BB * SS)

typedef __attribute__((ext_vector_type(8))) short bf16x8;
typedef __attribute__((ext_vector_type(4))) float f32x4;

static __device__ __forceinline__ short f2bf(float x) {
    union { __hip_bfloat16 h; short s; } u;
    u.h = __float2bfloat16(x);
    return u.s;
}

#define GL_LDS16(gp, lp)                                                      \
    __builtin_amdgcn_global_load_lds(                                         \
        (const __attribute__((address_space(1))) void*)(gp),                  \
        (__attribute__((address_space(3))) void*)(lp), 16, 0, 0)

// ---------------------------------------------------------------------------
// Weight transpose+convert: W [K,N] f32 -> Wt [N,K] bf16. 64x64 tiles.
__global__ __launch_bounds__(256) void transposeW3(const float* __restrict__ W0,
                                                   const float* __restrict__ W1,
                                                   const float* __restrict__ W2,
                                                   short* __restrict__ Wt) {
    const int z = blockIdx.z;
    const float* W = (z == 0) ? W0 : (z == 1) ? W1 : W2;
    short* dst = Wt + (size_t)z * DDIM * DDIM;
    __shared__ short sT[64][72];
    const int t = threadIdx.x;
    const int k0 = blockIdx.y * 64, n0 = blockIdx.x * 64;
    {
        int r = t >> 2, cq = (t & 3) << 4;
        const float* p = W + (size_t)(k0 + r) * DDIM + n0 + cq;
        float4 a = ((const float4*)p)[0], b = ((const float4*)p)[1];
        float4 c = ((const float4*)p)[2], d = ((const float4*)p)[3];
        short* dp = &sT[r][cq];
        dp[0]  = f2bf(a.x); dp[1]  = f2bf(a.y); dp[2]  = f2bf(a.z); dp[3]  = f2bf(a.w);
        dp[4]  = f2bf(b.x); dp[5]  = f2bf(b.y); dp[6]  = f2bf(b.z); dp[7]  = f2bf(b.w);
        dp[8]  = f2bf(c.x); dp[9]  = f2bf(c.y); dp[10] = f2bf(c.z); dp[11] = f2bf(c.w);
        dp[12] = f2bf(d.x); dp[13] = f2bf(d.y); dp[14] = f2bf(d.z); dp[15] = f2bf(d.w);
    }
    __syncthreads();
    {
        int n = t >> 2, kq = (t & 3) << 4;
        bf16x8 o0, o1;
#pragma unroll
        for (int j = 0; j < 8; ++j) o0[j] = sT[kq + j][n];
#pragma unroll
        for (int j = 0; j < 8; ++j) o1[j] = sT[kq + 8 + j][n];
        short* q = dst + (size_t)(n0 + n) * DDIM + k0 + kq;
        *(bf16x8*)q = o0;
        *(bf16x8*)(q + 8) = o1;
    }
}

// ---------------------------------------------------------------------------
// C[z][M,N] = A[z][M,K] @ Bt[z][N,K]^T, up to 3 fused problems.
// BM=128, BN template (64 -> grid 512/problem -> 6 blocks/CU for QKV),
// BK=32 double-buffered, XOR swizzle slot' = s ^ (row&3) on 16B slots,
// XCD-chunked. 256 thr = 4 waves (2x2), wave tile 64 x BN/2.
template<bool A_F32, bool C_F32, int BN>
__global__ __launch_bounds__(256) void gemm(const void* __restrict__ A0v,
                                            const void* __restrict__ A1v,
                                            const void* __restrict__ A2v,
                                            const short* __restrict__ BtBase,
                                            void* __restrict__ C0v,
                                            void* __restrict__ C1v,
                                            void* __restrict__ C2v) {
    constexpr int NJ  = BN / 32;        // acc cols per wave
    constexpr int NBX = DDIM / BN;      // col panels
    constexpr int NPB = 32 * NBX;       // blocks per problem
    constexpr int BCH = BN / 64;        // B chunks per thread

    __shared__ short sA[2][128 * 32];   // 8 KB per buf
    __shared__ short sB[2][BN * 32];    // 4 KB per buf @ BN=64

    const int tid = threadIdx.x;
    const int lane = tid & 63, wid = tid >> 6;
    const int wr = wid >> 1, wc = wid & 1;
    const int g = lane >> 4, l15 = lane & 15;

    const int blk = blockIdx.x;
    const int z = blk / NPB;
    const int inner = blk % NPB;
    const int xcd = inner & 7, ii = inner >> 3;   // ii in [0, 4*NBX)
    const int by = xcd * 4 + ii / NBX;            // 32 row panels, 4 per XCD
    const int bx = ii % NBX;

    const void* Av = (z == 0) ? A0v : (z == 1) ? A1v : A2v;
    const short* Bt = BtBase + (size_t)z * DDIM * DDIM;
    void* Cv = (z == 0) ? C0v : (z == 1) ? C1v : C2v;
    const float* Af = (const float*)Av;
    const short* Ab = (const short*)Av;
    const int K = DDIM;

    f32x4 acc[4][NJ] = {};
    const int nkt = K >> 5;   // 32 K-steps

    // ---- prologue: stage tile 0 into buf 0 ----
    if constexpr (A_F32) {
#pragma unroll
        for (int j = 0; j < 2; ++j) {
            int c = tid + j * 256;
            int row = c >> 2, s = c & 3;
            const float* p = Af + (size_t)(by * 128 + row) * K + s * 8;
            float4 x0 = ((const float4*)p)[0];
            float4 x1 = ((const float4*)p)[1];
            bf16x8 vv;
            vv[0] = f2bf(x0.x); vv[1] = f2bf(x0.y); vv[2] = f2bf(x0.z); vv[3] = f2bf(x0.w);
            vv[4] = f2bf(x1.x); vv[5] = f2bf(x1.y); vv[6] = f2bf(x1.z); vv[7] = f2bf(x1.w);
            *(bf16x8*)(&sA[0][row * 32 + ((s ^ (row & 3)) << 3)]) = vv;
        }
    } else {
#pragma unroll
        for (int j = 0; j < 2; ++j) {
            int c = tid + j * 256;
            int row = c >> 2, sp = c & 3;
            GL_LDS16(Ab + (size_t)(by * 128 + row) * K + ((sp ^ (row & 3)) << 3),
                     (char*)&sA[0][0] + c * 16);
        }
    }
#pragma unroll
    for (int j = 0; j < BCH; ++j) {
        int c = tid + j * 256;
        int row = c >> 2, sp = c & 3;
        GL_LDS16(Bt + (size_t)(bx * BN + row) * K + ((sp ^ (row & 3)) << 3),
                 (char*)&sB[0][0] + c * 16);
    }

    for (int t = 0; t < nkt; ++t) {
        const int cur = t & 1, nxt = cur ^ 1;
        __syncthreads();   // buf[cur] ready; prev reads of buf[nxt] done

        const bool pre = (t + 1 < nkt);
        float4 ra[2][2];
        if (pre) {
            const int kt = (t + 1) << 5;
            if constexpr (A_F32) {
#pragma unroll
                for (int j = 0; j < 2; ++j) {
                    int c = tid + j * 256;
                    int row = c >> 2, s = c & 3;
                    const float* p = Af + (size_t)(by * 128 + row) * K + kt + s * 8;
                    ra[j][0] = ((const float4*)p)[0];
                    ra[j][1] = ((const float4*)p)[1];
                }
            } else {
#pragma unroll
                for (int j = 0; j < 2; ++j) {
                    int c = tid + j * 256;
                    int row = c >> 2, sp = c & 3;
                    GL_LDS16(Ab + (size_t)(by * 128 + row) * K + kt + ((sp ^ (row & 3)) << 3),
                             (char*)&sA[nxt][0] + c * 16);
                }
            }
#pragma unroll
            for (int j = 0; j < BCH; ++j) {
                int c = tid + j * 256;
                int row = c >> 2, sp = c & 3;
                GL_LDS16(Bt + (size_t)(bx * BN + row) * K + kt + ((sp ^ (row & 3)) << 3),
                         (char*)&sB[nxt][0] + c * 16);
            }
        }

        bf16x8 af[4], bfr[NJ];
#pragma unroll
        for (int i = 0; i < 4; ++i) {
            int row = wr * 64 + i * 16 + l15;
            af[i] = *(const bf16x8*)(&sA[cur][row * 32 + ((g ^ (row & 3)) << 3)]);
        }
#pragma unroll
        for (int j = 0; j < NJ; ++j) {
            int row = wc * (BN / 2) + j * 16 + l15;
            bfr[j] = *(const bf16x8*)(&sB[cur][row * 32 + ((g ^ (row & 3)) << 3)]);
        }
#pragma unroll
        for (int i = 0; i < 4; ++i)
#pragma unroll
            for (int j = 0; j < NJ; ++j)
                acc[i][j] = __builtin_amdgcn_mfma_f32_16x16x32_bf16(af[i], bfr[j], acc[i][j], 0, 0, 0);

        if (pre) {
            if constexpr (A_F32) {
#pragma unroll
                for (int j = 0; j < 2; ++j) {
                    int c = tid + j * 256;
                    int row = c >> 2, s = c & 3;
                    bf16x8 vv;
                    vv[0] = f2bf(ra[j][0].x); vv[1] = f2bf(ra[j][0].y);
                    vv[2] = f2bf(ra[j][0].z); vv[3] = f2bf(ra[j][0].w);
                    vv[4] = f2bf(ra[j][1].x); vv[5] = f2bf(ra[j][1].y);
                    vv[6] = f2bf(ra[j][1].z); vv[7] = f2bf(ra[j][1].w);
                    *(bf16x8*)(&sA[nxt][row * 32 + ((s ^ (row & 3)) << 3)]) = vv;
                }
            }
        }
    }

#pragma unroll
    for (int i = 0; i < 4; ++i)
#pragma unroll
        for (int j = 0; j < NJ; ++j)
#pragma unroll
            for (int r = 0; r < 4; ++r) {
                int row = by * 128 + wr * 64 + i * 16 + g * 4 + r;
                int col = bx * BN + wc * (BN / 2) + j * 16 + l15;
                if constexpr (C_F32)
                    ((float*)Cv)[(size_t)row * DDIM + col] = acc[i][j][r];
                else
                    ((short*)Cv)[(size_t)row * DDIM + col] = f2bf(acc[i][j][r]);
            }
}

// ---------------------------------------------------------------------------
// Flash attention per (b, h, 64-q-rows). 4 waves x 16 q-rows, KV tiles of 64.
// Batch-interleaved block order (load balance); swizzled sK/sV/sP; K staged
// via global_load_lds (pre-swizzled source); 2 barriers per 64-key tile.
__global__ __launch_bounds__(256) void attn(const short* __restrict__ q,
                                            const short* __restrict__ k,
                                            const short* __restrict__ v,
                                            const int* __restrict__ vlens,
                                            short* __restrict__ att) {
    const int blk = blockIdx.x;            // 1024
    const int qt = blk >> 6;               // 0..15
    const int hb = blk & 63;
    const int bb = hb & 3;                 // batch varies fastest
    const int h  = hb >> 2;

    const int tid = threadIdx.x;
    const int lane = tid & 63, wid = tid >> 6;
    const int g = lane >> 4, l15 = lane & 15;
    const int vlen = vlens[bb];

    __shared__ short sK[64 * 64];          // [key][d-slots], swz by key&7
    __shared__ short sV[64 * 64];          // [e][key-slots], swz by e&7
    __shared__ short sP[4][16 * 64];       // per-wave [q][key-slots], swz by q&7

    const int srow = qt * 64 + wid * 16 + l15;
    const short* qrow = q + ((size_t)(bb * SS + srow)) * DDIM + h * 64;
    bf16x8 qf[2];
    qf[0] = *(const bf16x8*)(qrow + g * 8);
    qf[1] = *(const bf16x8*)(qrow + 32 + g * 8);

    float m_run[4], l_run[4];
#pragma unroll
    for (int r = 0; r < 4; ++r) { m_run[r] = -1e30f; l_run[r] = 0.0f; }
    f32x4 oacc[4] = {};

    const int ntiles = (vlen + 63) >> 6;
    for (int t = 0; t < ntiles; ++t) {
        const int kb = t * 64;
        __syncthreads();   // prev tile's reads complete
        {
#pragma unroll
            for (int j = 0; j < 2; ++j) {
                int c = tid + j * 256;
                int key = c >> 3, sp = c & 7;
                GL_LDS16(k + ((size_t)(bb * SS + kb + key)) * DDIM + h * 64 +
                             ((sp ^ (key & 7)) << 3),
                         (char*)&sK[0] + c * 16);
            }
#pragma unroll
            for (int j = 0; j < 2; ++j) {
                int c = tid + j * 256;
                int key = c >> 3, d0 = (c & 7) << 3;
                bf16x8 vv = *(const bf16x8*)(v + ((size_t)(bb * SS + kb + key)) * DDIM + h * 64 + d0);
#pragma unroll
                for (int e = 0; e < 8; ++e) {
                    int ee = d0 + e;
                    sV[ee * 64 + (((key >> 3) ^ (ee & 7)) << 3) + (key & 7)] = vv[e];
                }
            }
        }
        __syncthreads();

        // QK^T: 16 q-rows x 64 keys per wave
        f32x4 sacc[4] = {};
#pragma unroll
        for (int kg = 0; kg < 4; ++kg) {
            int row = kg * 16 + l15;
#pragma unroll
            for (int kh = 0; kh < 2; ++kh) {
                int s = kh * 4 + g;
                bf16x8 kf = *(const bf16x8*)(&sK[row * 64 + ((s ^ (row & 7)) << 3)]);
                sacc[kg] = __builtin_amdgcn_mfma_f32_16x16x32_bf16(qf[kh], kf, sacc[kg], 0, 0, 0);
            }
        }

        // online softmax
        float f[4];
#pragma unroll
        for (int r = 0; r < 4; ++r) {
            float s[4];
#pragma unroll
            for (int kg = 0; kg < 4; ++kg) {
                s[kg] = sacc[kg][r] * 0.125f;
                if (kb + kg * 16 + l15 >= vlen) s[kg] = -1e30f;
            }
            float tmax = fmaxf(fmaxf(s[0], s[1]), fmaxf(s[2], s[3]));
#pragma unroll
            for (int off = 1; off < 16; off <<= 1)
                tmax = fmaxf(tmax, __shfl_xor(tmax, off));
            float mn = fmaxf(m_run[r], tmax);
            f[r] = __expf(m_run[r] - mn);
            m_run[r] = mn;
            float p[4], rs = 0.0f;
#pragma unroll
            for (int kg = 0; kg < 4; ++kg) { p[kg] = __expf(s[kg] - mn); rs += p[kg]; }
#pragma unroll
            for (int off = 1; off < 16; off <<= 1)
                rs += __shfl_xor(rs, off);
            l_run[r] = l_run[r] * f[r] + rs;
            const int srw = g * 4 + r;
#pragma unroll
            for (int kg = 0; kg < 4; ++kg) {
                int col = kg * 16 + l15;
                sP[wid][srw * 64 + (((col >> 3) ^ (srw & 7)) << 3) + (col & 7)] = f2bf(p[kg]);
            }
        }
        // no barrier: sP wave-private; sK/sV protected by next-iter barrier

        // PV
        bf16x8 pf[2];
#pragma unroll
        for (int kh = 0; kh < 2; ++kh) {
            int s = kh * 4 + g;
            pf[kh] = *(const bf16x8*)(&sP[wid][l15 * 64 + ((s ^ (l15 & 7)) << 3)]);
        }
#pragma unroll
        for (int n = 0; n < 4; ++n) {
#pragma unroll
            for (int r = 0; r < 4; ++r) oacc[n][r] *= f[r];
            const int e = n * 16 + l15;
#pragma unroll
            for (int kh = 0; kh < 2; ++kh) {
                int s = kh * 4 + g;
                bf16x8 vf = *(const bf16x8*)(&sV[e * 64 + ((s ^ (e & 7)) << 3)]);
                oacc[n] = __builtin_amdgcn_mfma_f32_16x16x32_bf16(pf[kh], vf, oacc[n], 0, 0, 0);
            }
        }
    }

    // write head-interleaved: att[bb][s][e*H + h]
#pragma unroll
    for (int n = 0; n < 4; ++n)
#pragma unroll
        for (int r = 0; r < 4; ++r) {
            float o = oacc[n][r] / l_run[r];
            int sg = qt * 64 + wid * 16 + g * 4 + r;
            int e = n * 16 + l15;
            att[((size_t)(bb * SS + sg)) * DDIM + e * HH + h] = f2bf(o);
        }
}

extern "C" void kernel_launch(void* const* d_in, const int* in_sizes, int n_in,
                              void* d_out, int out_size, void* d_ws, size_t ws_size,
                              hipStream_t stream) {
    const float* queries = (const float*)d_in[0];
    const float* keys    = (const float*)d_in[1];
    const float* values  = (const float*)d_in[2];
    const int*   vlens   = (const int*)d_in[3];
    const float* Wq      = (const float*)d_in[4];
    const float* Wk      = (const float*)d_in[5];
    const float* Wv      = (const float*)d_in[6];
    const float* Wo      = (const float*)d_in[7];
    float* out = (float*)d_out;

    short* ws = (short*)d_ws;
    const size_t sz = (size_t)MROWS * DDIM;   // 4M elems
    short* q_ws   = ws;
    short* k_ws   = ws + sz;
    short* v_ws   = ws + 2 * sz;
    short* att_ws = ws + 3 * sz;
    short* wt3  = att_ws;                     // weights; dead until attn writes
    short* wt_o = q_ws;                       // dead after attn

    dim3 tgrid3(16, 16, 3);
    dim3 tgrid1(16, 16, 1);

    transposeW3<<<tgrid3, 256, 0, stream>>>(Wq, Wk, Wv, wt3);
    // BN=64 -> 512 blocks/problem, 1536 total = 6 blocks/CU (latency hiding)
    gemm<true, false, 64><<<dim3(1536), 256, 0, stream>>>(queries, keys, values, wt3,
                                                          q_ws, k_ws, v_ws);
    attn<<<dim3(1024), 256, 0, stream>>>(q_ws, k_ws, v_ws, vlens, att_ws);

    transposeW3<<<tgrid1, 256, 0, stream>>>(Wo, Wo, Wo, wt_o);
    gemm<false, true, 64><<<dim3(512), 256, 0, stream>>>(att_ws, att_ws, att_ws, wt_o,
                                                         out, out, out);
}

// Round 9
// 131.552 us; speedup vs baseline: 1.1353x; 1.1353x over previous
//
#include <hip/hip_runtime.h>
#include <hip/hip_bf16.h>

#define BB 4
#define SS 1024
#define DDIM 1024
#define HH 16
#define MROWS (BB * SS)

typedef __attribute__((ext_vector_type(8))) short bf16x8;
typedef __attribute__((ext_vector_type(4))) float f32x4;

static __device__ __forceinline__ short f2bf(float x) {
    union { __hip_bfloat16 h; short s; } u;
    u.h = __float2bfloat16(x);
    return u.s;
}

#define GL_LDS16(gp, lp)                                                      \
    __builtin_amdgcn_global_load_lds(                                         \
        (const __attribute__((address_space(1))) void*)(gp),                  \
        (__attribute__((address_space(3))) void*)(lp), 16, 0, 0)

// BK=32 swizzle: physical 16B slot = s ^ ((row>>1)&3). 64B rows alias banks
// by (row&1, slot); this XOR spreads each 8-lane b128 phase over 8 stripes.
#define SWZ4(row, s) ((((s) ^ (((row) >> 1) & 3))) << 3)

// ---------------------------------------------------------------------------
// f32 [MROWS,DDIM] -> bf16, 3 tensors (z). Skips K/V rows >= vlen (2-row grain).
__global__ __launch_bounds__(256) void cvtA3(const float* __restrict__ X0,
                                             const float* __restrict__ X1,
                                             const float* __restrict__ X2,
                                             short* __restrict__ dst,
                                             const int* __restrict__ vlens) {
    const int z = blockIdx.y;
    const int blk = blockIdx.x;          // 2048 blocks x 2048 elems (2 rows)
    const int row0 = blk << 1;
    if (z >= 1) {
        const int bb = row0 >> 10;
        if ((row0 & 1023) >= vlens[bb]) return;   // both rows dead downstream
    }
    const float* X = (z == 0) ? X0 : (z == 1) ? X1 : X2;
    short* D = dst + (size_t)z * MROWS * DDIM;
    const size_t base = (size_t)blk * 2048 + threadIdx.x * 8;
    const float4 x0 = ((const float4*)(X + base))[0];
    const float4 x1 = ((const float4*)(X + base))[1];
    bf16x8 vv;
    vv[0] = f2bf(x0.x); vv[1] = f2bf(x0.y); vv[2] = f2bf(x0.z); vv[3] = f2bf(x0.w);
    vv[4] = f2bf(x1.x); vv[5] = f2bf(x1.y); vv[6] = f2bf(x1.z); vv[7] = f2bf(x1.w);
    *(bf16x8*)(D + base) = vv;
}

// ---------------------------------------------------------------------------
// Weight transpose+convert: W [K,N] f32 -> Wt [N,K] bf16. 64x64 tiles.
__global__ __launch_bounds__(256) void transposeW3(const float* __restrict__ W0,
                                                   const float* __restrict__ W1,
                                                   const float* __restrict__ W2,
                                                   short* __restrict__ Wt) {
    const int z = blockIdx.z;
    const float* W = (z == 0) ? W0 : (z == 1) ? W1 : W2;
    short* dst = Wt + (size_t)z * DDIM * DDIM;
    __shared__ short sT[64][72];
    const int t = threadIdx.x;
    const int k0 = blockIdx.y * 64, n0 = blockIdx.x * 64;
    {
        int r = t >> 2, cq = (t & 3) << 4;
        const float* p = W + (size_t)(k0 + r) * DDIM + n0 + cq;
        float4 a = ((const float4*)p)[0], b = ((const float4*)p)[1];
        float4 c = ((const float4*)p)[2], d = ((const float4*)p)[3];
        short* dp = &sT[r][cq];
        dp[0]  = f2bf(a.x); dp[1]  = f2bf(a.y); dp[2]  = f2bf(a.z); dp[3]  = f2bf(a.w);
        dp[4]  = f2bf(b.x); dp[5]  = f2bf(b.y); dp[6]  = f2bf(b.z); dp[7]  = f2bf(b.w);
        dp[8]  = f2bf(c.x); dp[9]  = f2bf(c.y); dp[10] = f2bf(c.z); dp[11] = f2bf(c.w);
        dp[12] = f2bf(d.x); dp[13] = f2bf(d.y); dp[14] = f2bf(d.z); dp[15] = f2bf(d.w);
    }
    __syncthreads();
    {
        int n = t >> 2, kq = (t & 3) << 4;
        bf16x8 o0, o1;
#pragma unroll
        for (int j = 0; j < 8; ++j) o0[j] = sT[kq + j][n];
#pragma unroll
        for (int j = 0; j < 8; ++j) o1[j] = sT[kq + 8 + j][n];
        short* q = dst + (size_t)(n0 + n) * DDIM + k0 + kq;
        *(bf16x8*)q = o0;
        *(bf16x8*)(q + 8) = o1;
    }
}

// ---------------------------------------------------------------------------
// C[z][M,N] = A[z][M,K] @ Bt[z][N,K]^T, up to 3 fused problems.
// BM=128, BN template, BK=32 double-buffered. A bf16 path = pure
// global_load_lds (no VALU staging). SKIP: K/V tiles with all rows >= vlen
// exit immediately (outputs never read unmasked downstream).
template<bool A_F32, bool C_F32, int BN, bool SKIP>
__global__ __launch_bounds__(256) void gemm(const void* __restrict__ A0v,
                                            const void* __restrict__ A1v,
                                            const void* __restrict__ A2v,
                                            const short* __restrict__ BtBase,
                                            void* __restrict__ C0v,
                                            void* __restrict__ C1v,
                                            void* __restrict__ C2v,
                                            const int* __restrict__ vlens) {
    constexpr int NJ  = BN / 32;        // acc cols per wave
    constexpr int NBX = DDIM / BN;      // col panels
    constexpr int NPB = 32 * NBX;       // blocks per problem
    constexpr int BCH = BN / 64;        // B chunks per thread

    __shared__ short sA[2][128 * 32];   // 8 KB per buf
    __shared__ short sB[2][BN * 32];

    const int tid = threadIdx.x;
    const int lane = tid & 63, wid = tid >> 6;
    const int wr = wid >> 1, wc = wid & 1;
    const int g = lane >> 4, l15 = lane & 15;

    const int blk = blockIdx.x;
    const int z = blk / NPB;
    const int inner = blk % NPB;
    const int xcd = inner & 7, ii = inner >> 3;
    const int by = xcd * 4 + ii / NBX;            // 32 row panels, 4 per XCD
    const int bx = ii % NBX;

    if constexpr (SKIP) {
        if (z >= 1 && ((by & 7) << 7) >= vlens[by >> 3]) return;
    }

    const void* Av = (z == 0) ? A0v : (z == 1) ? A1v : A2v;
    const short* Bt = BtBase + (size_t)z * DDIM * DDIM;
    void* Cv = (z == 0) ? C0v : (z == 1) ? C1v : C2v;
    const float* Af = (const float*)Av;
    const short* Ab = (const short*)Av;
    const int K = DDIM;

    f32x4 acc[4][NJ] = {};
    const int nkt = K >> 5;   // 32 K-steps

    // ---- prologue: stage tile 0 into buf 0 ----
    if constexpr (A_F32) {
#pragma unroll
        for (int j = 0; j < 2; ++j) {
            int c = tid + j * 256;
            int row = c >> 2, s = c & 3;
            const float* p = Af + (size_t)(by * 128 + row) * K + s * 8;
            float4 x0 = ((const float4*)p)[0];
            float4 x1 = ((const float4*)p)[1];
            bf16x8 vv;
            vv[0] = f2bf(x0.x); vv[1] = f2bf(x0.y); vv[2] = f2bf(x0.z); vv[3] = f2bf(x0.w);
            vv[4] = f2bf(x1.x); vv[5] = f2bf(x1.y); vv[6] = f2bf(x1.z); vv[7] = f2bf(x1.w);
            *(bf16x8*)(&sA[0][row * 32 + SWZ4(row, s)]) = vv;
        }
    } else {
#pragma unroll
        for (int j = 0; j < 2; ++j) {
            int c = tid + j * 256;
            int row = c >> 2, sp = c & 3;
            GL_LDS16(Ab + (size_t)(by * 128 + row) * K + SWZ4(row, sp),
                     (char*)&sA[0][0] + c * 16);
        }
    }
#pragma unroll
    for (int j = 0; j < BCH; ++j) {
        int c = tid + j * 256;
        int row = c >> 2, sp = c & 3;
        GL_LDS16(Bt + (size_t)(bx * BN + row) * K + SWZ4(row, sp),
                 (char*)&sB[0][0] + c * 16);
    }

    for (int t = 0; t < nkt; ++t) {
        const int cur = t & 1, nxt = cur ^ 1;
        __syncthreads();   // buf[cur] ready; prev reads of buf[nxt] done

        const bool pre = (t + 1 < nkt);
        float4 ra[2][2];
        if (pre) {
            const int kt = (t + 1) << 5;
            if constexpr (A_F32) {
#pragma unroll
                for (int j = 0; j < 2; ++j) {
                    int c = tid + j * 256;
                    int row = c >> 2, s = c & 3;
                    const float* p = Af + (size_t)(by * 128 + row) * K + kt + s * 8;
                    ra[j][0] = ((const float4*)p)[0];
                    ra[j][1] = ((const float4*)p)[1];
                }
            } else {
#pragma unroll
                for (int j = 0; j < 2; ++j) {
                    int c = tid + j * 256;
                    int row = c >> 2, sp = c & 3;
                    GL_LDS16(Ab + (size_t)(by * 128 + row) * K + kt + SWZ4(row, sp),
                             (char*)&sA[nxt][0] + c * 16);
                }
            }
#pragma unroll
            for (int j = 0; j < BCH; ++j) {
                int c = tid + j * 256;
                int row = c >> 2, sp = c & 3;
                GL_LDS16(Bt + (size_t)(bx * BN + row) * K + kt + SWZ4(row, sp),
                         (char*)&sB[nxt][0] + c * 16);
            }
        }

        bf16x8 af[4], bfr[NJ];
#pragma unroll
        for (int i = 0; i < 4; ++i) {
            int row = wr * 64 + i * 16 + l15;
            af[i] = *(const bf16x8*)(&sA[cur][row * 32 + SWZ4(row, g)]);
        }
#pragma unroll
        for (int j = 0; j < NJ; ++j) {
            int row = wc * (BN / 2) + j * 16 + l15;
            bfr[j] = *(const bf16x8*)(&sB[cur][row * 32 + SWZ4(row, g)]);
        }
#pragma unroll
        for (int i = 0; i < 4; ++i)
#pragma unroll
            for (int j = 0; j < NJ; ++j)
                acc[i][j] = __builtin_amdgcn_mfma_f32_16x16x32_bf16(af[i], bfr[j], acc[i][j], 0, 0, 0);

        if (pre) {
            if constexpr (A_F32) {
#pragma unroll
                for (int j = 0; j < 2; ++j) {
                    int c = tid + j * 256;
                    int row = c >> 2, s = c & 3;
                    bf16x8 vv;
                    vv[0] = f2bf(ra[j][0].x); vv[1] = f2bf(ra[j][0].y);
                    vv[2] = f2bf(ra[j][0].z); vv[3] = f2bf(ra[j][0].w);
                    vv[4] = f2bf(ra[j][1].x); vv[5] = f2bf(ra[j][1].y);
                    vv[6] = f2bf(ra[j][1].z); vv[7] = f2bf(ra[j][1].w);
                    *(bf16x8*)(&sA[nxt][row * 32 + SWZ4(row, s)]) = vv;
                }
            }
        }
    }

#pragma unroll
    for (int i = 0; i < 4; ++i)
#pragma unroll
        for (int j = 0; j < NJ; ++j)
#pragma unroll
            for (int r = 0; r < 4; ++r) {
                int row = by * 128 + wr * 64 + i * 16 + g * 4 + r;
                int col = bx * BN + wc * (BN / 2) + j * 16 + l15;
                if constexpr (C_F32)
                    ((float*)Cv)[(size_t)row * DDIM + col] = acc[i][j][r];
                else
                    ((short*)Cv)[(size_t)row * DDIM + col] = f2bf(acc[i][j][r]);
            }
}

// ---------------------------------------------------------------------------
// Flash attention per (b, h, 64-q-rows). 4 waves x 16 q-rows, KV tiles of 64.
// Batch-interleaved block order; swizzled sK/sV/sP; K via global_load_lds.
__global__ __launch_bounds__(256) void attn(const short* __restrict__ q,
                                            const short* __restrict__ k,
                                            const short* __restrict__ v,
                                            const int* __restrict__ vlens,
                                            short* __restrict__ att) {
    const int blk = blockIdx.x;            // 1024
    const int qt = blk >> 6;               // 0..15
    const int hb = blk & 63;
    const int bb = hb & 3;                 // batch varies fastest
    const int h  = hb >> 2;

    const int tid = threadIdx.x;
    const int lane = tid & 63, wid = tid >> 6;
    const int g = lane >> 4, l15 = lane & 15;
    const int vlen = vlens[bb];

    __shared__ short sK[64 * 64];          // [key][d-slots], swz by key&7
    __shared__ short sV[64 * 64];          // [e][key-slots], swz by e&7
    __shared__ short sP[4][16 * 64];       // per-wave [q][key-slots], swz by q&7

    const int srow = qt * 64 + wid * 16 + l15;
    const short* qrow = q + ((size_t)(bb * SS + srow)) * DDIM + h * 64;
    bf16x8 qf[2];
    qf[0] = *(const bf16x8*)(qrow + g * 8);
    qf[1] = *(const bf16x8*)(qrow + 32 + g * 8);

    float m_run[4], l_run[4];
#pragma unroll
    for (int r = 0; r < 4; ++r) { m_run[r] = -1e30f; l_run[r] = 0.0f; }
    f32x4 oacc[4] = {};

    const int ntiles = (vlen + 63) >> 6;
    for (int t = 0; t < ntiles; ++t) {
        const int kb = t * 64;
        __syncthreads();   // prev tile's reads complete
        {
#pragma unroll
            for (int j = 0; j < 2; ++j) {
                int c = tid + j * 256;
                int key = c >> 3, sp = c & 7;
                GL_LDS16(k + ((size_t)(bb * SS + kb + key)) * DDIM + h * 64 +
                             ((sp ^ (key & 7)) << 3),
                         (char*)&sK[0] + c * 16);
            }
#pragma unroll
            for (int j = 0; j < 2; ++j) {
                int c = tid + j * 256;
                int key = c >> 3, d0 = (c & 7) << 3;
                bf16x8 vv = *(const bf16x8*)(v + ((size_t)(bb * SS + kb + key)) * DDIM + h * 64 + d0);
#pragma unroll
                for (int e = 0; e < 8; ++e) {
                    int ee = d0 + e;
                    sV[ee * 64 + (((key >> 3) ^ (ee & 7)) << 3) + (key & 7)] = vv[e];
                }
            }
        }
        __syncthreads();

        // QK^T: 16 q-rows x 64 keys per wave
        f32x4 sacc[4] = {};
#pragma unroll
        for (int kg = 0; kg < 4; ++kg) {
            int row = kg * 16 + l15;
#pragma unroll
            for (int kh = 0; kh < 2; ++kh) {
                int s = kh * 4 + g;
                bf16x8 kf = *(const bf16x8*)(&sK[row * 64 + ((s ^ (row & 7)) << 3)]);
                sacc[kg] = __builtin_amdgcn_mfma_f32_16x16x32_bf16(qf[kh], kf, sacc[kg], 0, 0, 0);
            }
        }

        // online softmax
        float f[4];
#pragma unroll
        for (int r = 0; r < 4; ++r) {
            float s[4];
#pragma unroll
            for (int kg = 0; kg < 4; ++kg) {
                s[kg] = sacc[kg][r] * 0.125f;
                if (kb + kg * 16 + l15 >= vlen) s[kg] = -1e30f;
            }
            float tmax = fmaxf(fmaxf(s[0], s[1]), fmaxf(s[2], s[3]));
#pragma unroll
            for (int off = 1; off < 16; off <<= 1)
                tmax = fmaxf(tmax, __shfl_xor(tmax, off));
            float mn = fmaxf(m_run[r], tmax);
            f[r] = __expf(m_run[r] - mn);
            m_run[r] = mn;
            float p[4], rs = 0.0f;
#pragma unroll
            for (int kg = 0; kg < 4; ++kg) { p[kg] = __expf(s[kg] - mn); rs += p[kg]; }
#pragma unroll
            for (int off = 1; off < 16; off <<= 1)
                rs += __shfl_xor(rs, off);
            l_run[r] = l_run[r] * f[r] + rs;
            const int srw = g * 4 + r;
#pragma unroll
            for (int kg = 0; kg < 4; ++kg) {
                int col = kg * 16 + l15;
                sP[wid][srw * 64 + (((col >> 3) ^ (srw & 7)) << 3) + (col & 7)] = f2bf(p[kg]);
            }
        }
        // no barrier: sP wave-private; sK/sV protected by next-iter barrier

        // PV
        bf16x8 pf[2];
#pragma unroll
        for (int kh = 0; kh < 2; ++kh) {
            int s = kh * 4 + g;
            pf[kh] = *(const bf16x8*)(&sP[wid][l15 * 64 + ((s ^ (l15 & 7)) << 3)]);
        }
#pragma unroll
        for (int n = 0; n < 4; ++n) {
#pragma unroll
            for (int r = 0; r < 4; ++r) oacc[n][r] *= f[r];
            const int e = n * 16 + l15;
#pragma unroll
            for (int kh = 0; kh < 2; ++kh) {
                int s = kh * 4 + g;
                bf16x8 vf = *(const bf16x8*)(&sV[e * 64 + ((s ^ (e & 7)) << 3)]);
                oacc[n] = __builtin_amdgcn_mfma_f32_16x16x32_bf16(pf[kh], vf, oacc[n], 0, 0, 0);
            }
        }
    }

    // write head-interleaved: att[bb][s][e*H + h]
#pragma unroll
    for (int n = 0; n < 4; ++n)
#pragma unroll
        for (int r = 0; r < 4; ++r) {
            float o = oacc[n][r] / l_run[r];
            int sg = qt * 64 + wid * 16 + g * 4 + r;
            int e = n * 16 + l15;
            att[((size_t)(bb * SS + sg)) * DDIM + e * HH + h] = f2bf(o);
        }
}

extern "C" void kernel_launch(void* const* d_in, const int* in_sizes, int n_in,
                              void* d_out, int out_size, void* d_ws, size_t ws_size,
                              hipStream_t stream) {
    const float* queries = (const float*)d_in[0];
    const float* keys    = (const float*)d_in[1];
    const float* values  = (const float*)d_in[2];
    const int*   vlens   = (const int*)d_in[3];
    const float* Wq      = (const float*)d_in[4];
    const float* Wk      = (const float*)d_in[5];
    const float* Wv      = (const float*)d_in[6];
    const float* Wo      = (const float*)d_in[7];
    float* out = (float*)d_out;

    short* ws = (short*)d_ws;
    const size_t sz = (size_t)MROWS * DDIM;   // 4M elems
    short* q_ws   = ws;
    short* k_ws   = ws + sz;
    short* v_ws   = ws + 2 * sz;
    short* att_ws = ws + 3 * sz;
    short* wt3  = att_ws;                     // weights; dead until attn writes
    short* wt_o = q_ws;                       // dead after attn

    dim3 tgrid3(16, 16, 3);
    dim3 tgrid1(16, 16, 1);

    const bool big = ws_size >= (size_t)7 * sz * sizeof(short);   // 56 MB
    if (big) {
        short* qb = ws + 4 * sz;
        short* kb = ws + 5 * sz;
        short* vb = ws + 6 * sz;
        cvtA3<<<dim3(2048, 3), 256, 0, stream>>>(queries, keys, values, qb, vlens);
        transposeW3<<<tgrid3, 256, 0, stream>>>(Wq, Wk, Wv, wt3);
        gemm<false, false, 128, true><<<dim3(768), 256, 0, stream>>>(
            qb, kb, vb, wt3, q_ws, k_ws, v_ws, vlens);
    } else {
        transposeW3<<<tgrid3, 256, 0, stream>>>(Wq, Wk, Wv, wt3);
        gemm<true, false, 128, true><<<dim3(768), 256, 0, stream>>>(
            queries, keys, values, wt3, q_ws, k_ws, v_ws, vlens);
    }

    attn<<<dim3(1024), 256, 0, stream>>>(q_ws, k_ws, v_ws, vlens, att_ws);

    transposeW3<<<tgrid1, 256, 0, stream>>>(Wo, Wo, Wo, wt_o);
    gemm<false, true, 64, false><<<dim3(512), 256, 0, stream>>>(
        att_ws, att_ws, att_ws, wt_o, out, out, out, vlens);
}

// Round 10
// 130.552 us; speedup vs baseline: 1.1440x; 1.0077x over previous
//
#include <hip/hip_runtime.h>
#include <hip/hip_bf16.h>

#define BB 4
#define SS 1024
#define DDIM 1024
#define HH 16
#define MROWS (BB * SS)

typedef __attribute__((ext_vector_type(8))) short bf16x8;
typedef __attribute__((ext_vector_type(4))) float f32x4;

static __device__ __forceinline__ short f2bf(float x) {
    union { __hip_bfloat16 h; short s; } u;
    u.h = __float2bfloat16(x);
    return u.s;
}

#define GL_LDS16(gp, lp)                                                      \
    __builtin_amdgcn_global_load_lds(                                         \
        (const __attribute__((address_space(1))) void*)(gp),                  \
        (__attribute__((address_space(3))) void*)(lp), 16, 0, 0)

// BK=32 swizzle: physical 16B slot = s ^ ((row>>1)&3).
#define SWZ4(row, s) ((((s) ^ (((row) >> 1) & 3))) << 3)

// ---------------------------------------------------------------------------
// f32 [MROWS,DDIM] -> bf16, 3 tensors (z). Skips K/V rows >= vlen (2-row grain).
__global__ __launch_bounds__(256) void cvtA3(const float* __restrict__ X0,
                                             const float* __restrict__ X1,
                                             const float* __restrict__ X2,
                                             short* __restrict__ dst,
                                             const int* __restrict__ vlens) {
    const int z = blockIdx.y;
    const int blk = blockIdx.x;          // 2048 blocks x 2048 elems (2 rows)
    const int row0 = blk << 1;
    if (z >= 1) {
        const int bb = row0 >> 10;
        if ((row0 & 1023) >= vlens[bb]) return;   // both rows dead downstream
    }
    const float* X = (z == 0) ? X0 : (z == 1) ? X1 : X2;
    short* D = dst + (size_t)z * MROWS * DDIM;
    const size_t base = (size_t)blk * 2048 + threadIdx.x * 8;
    const float4 x0 = ((const float4*)(X + base))[0];
    const float4 x1 = ((const float4*)(X + base))[1];
    bf16x8 vv;
    vv[0] = f2bf(x0.x); vv[1] = f2bf(x0.y); vv[2] = f2bf(x0.z); vv[3] = f2bf(x0.w);
    vv[4] = f2bf(x1.x); vv[5] = f2bf(x1.y); vv[6] = f2bf(x1.z); vv[7] = f2bf(x1.w);
    *(bf16x8*)(D + base) = vv;
}

// ---------------------------------------------------------------------------
// Weight transpose+convert: W [K,N] f32 -> Wt [N,K] bf16. 64x64 tiles.
__global__ __launch_bounds__(256) void transposeW3(const float* __restrict__ W0,
                                                   const float* __restrict__ W1,
                                                   const float* __restrict__ W2,
                                                   short* __restrict__ Wt) {
    const int z = blockIdx.z;
    const float* W = (z == 0) ? W0 : (z == 1) ? W1 : W2;
    short* dst = Wt + (size_t)z * DDIM * DDIM;
    __shared__ short sT[64][72];
    const int t = threadIdx.x;
    const int k0 = blockIdx.y * 64, n0 = blockIdx.x * 64;
    {
        int r = t >> 2, cq = (t & 3) << 4;
        const float* p = W + (size_t)(k0 + r) * DDIM + n0 + cq;
        float4 a = ((const float4*)p)[0], b = ((const float4*)p)[1];
        float4 c = ((const float4*)p)[2], d = ((const float4*)p)[3];
        short* dp = &sT[r][cq];
        dp[0]  = f2bf(a.x); dp[1]  = f2bf(a.y); dp[2]  = f2bf(a.z); dp[3]  = f2bf(a.w);
        dp[4]  = f2bf(b.x); dp[5]  = f2bf(b.y); dp[6]  = f2bf(b.z); dp[7]  = f2bf(b.w);
        dp[8]  = f2bf(c.x); dp[9]  = f2bf(c.y); dp[10] = f2bf(c.z); dp[11] = f2bf(c.w);
        dp[12] = f2bf(d.x); dp[13] = f2bf(d.y); dp[14] = f2bf(d.z); dp[15] = f2bf(d.w);
    }
    __syncthreads();
    {
        int n = t >> 2, kq = (t & 3) << 4;
        bf16x8 o0, o1;
#pragma unroll
        for (int j = 0; j < 8; ++j) o0[j] = sT[kq + j][n];
#pragma unroll
        for (int j = 0; j < 8; ++j) o1[j] = sT[kq + 8 + j][n];
        short* q = dst + (size_t)(n0 + n) * DDIM + k0 + kq;
        *(bf16x8*)q = o0;
        *(bf16x8*)(q + 8) = o1;
    }
}

// ---------------------------------------------------------------------------
// C[z][M,N] = A[z][M,K] @ Bt[z][N,K]^T, up to 3 fused problems.
// BM=128, BN template, BK=32 double-buffered. A bf16 path = pure
// global_load_lds. SKIP: K/V tiles with all rows >= vlen exit immediately.
template<bool A_F32, bool C_F32, int BN, bool SKIP>
__global__ __launch_bounds__(256) void gemm(const void* __restrict__ A0v,
                                            const void* __restrict__ A1v,
                                            const void* __restrict__ A2v,
                                            const short* __restrict__ BtBase,
                                            void* __restrict__ C0v,
                                            void* __restrict__ C1v,
                                            void* __restrict__ C2v,
                                            const int* __restrict__ vlens) {
    constexpr int NJ  = BN / 32;
    constexpr int NBX = DDIM / BN;
    constexpr int NPB = 32 * NBX;
    constexpr int BCH = BN / 64;

    __shared__ short sA[2][128 * 32];
    __shared__ short sB[2][BN * 32];

    const int tid = threadIdx.x;
    const int lane = tid & 63, wid = tid >> 6;
    const int wr = wid >> 1, wc = wid & 1;
    const int g = lane >> 4, l15 = lane & 15;

    const int blk = blockIdx.x;
    const int z = blk / NPB;
    const int inner = blk % NPB;
    const int xcd = inner & 7, ii = inner >> 3;
    const int by = xcd * 4 + ii / NBX;
    const int bx = ii % NBX;

    if constexpr (SKIP) {
        if (z >= 1 && ((by & 7) << 7) >= vlens[by >> 3]) return;
    }

    const void* Av = (z == 0) ? A0v : (z == 1) ? A1v : A2v;
    const short* Bt = BtBase + (size_t)z * DDIM * DDIM;
    void* Cv = (z == 0) ? C0v : (z == 1) ? C1v : C2v;
    const float* Af = (const float*)Av;
    const short* Ab = (const short*)Av;
    const int K = DDIM;

    f32x4 acc[4][NJ] = {};
    const int nkt = K >> 5;

    if constexpr (A_F32) {
#pragma unroll
        for (int j = 0; j < 2; ++j) {
            int c = tid + j * 256;
            int row = c >> 2, s = c & 3;
            const float* p = Af + (size_t)(by * 128 + row) * K + s * 8;
            float4 x0 = ((const float4*)p)[0];
            float4 x1 = ((const float4*)p)[1];
            bf16x8 vv;
            vv[0] = f2bf(x0.x); vv[1] = f2bf(x0.y); vv[2] = f2bf(x0.z); vv[3] = f2bf(x0.w);
            vv[4] = f2bf(x1.x); vv[5] = f2bf(x1.y); vv[6] = f2bf(x1.z); vv[7] = f2bf(x1.w);
            *(bf16x8*)(&sA[0][row * 32 + SWZ4(row, s)]) = vv;
        }
    } else {
#pragma unroll
        for (int j = 0; j < 2; ++j) {
            int c = tid + j * 256;
            int row = c >> 2, sp = c & 3;
            GL_LDS16(Ab + (size_t)(by * 128 + row) * K + SWZ4(row, sp),
                     (char*)&sA[0][0] + c * 16);
        }
    }
#pragma unroll
    for (int j = 0; j < BCH; ++j) {
        int c = tid + j * 256;
        int row = c >> 2, sp = c & 3;
        GL_LDS16(Bt + (size_t)(bx * BN + row) * K + SWZ4(row, sp),
                 (char*)&sB[0][0] + c * 16);
    }

    for (int t = 0; t < nkt; ++t) {
        const int cur = t & 1, nxt = cur ^ 1;
        __syncthreads();

        const bool pre = (t + 1 < nkt);
        float4 ra[2][2];
        if (pre) {
            const int kt = (t + 1) << 5;
            if constexpr (A_F32) {
#pragma unroll
                for (int j = 0; j < 2; ++j) {
                    int c = tid + j * 256;
                    int row = c >> 2, s = c & 3;
                    const float* p = Af + (size_t)(by * 128 + row) * K + kt + s * 8;
                    ra[j][0] = ((const float4*)p)[0];
                    ra[j][1] = ((const float4*)p)[1];
                }
            } else {
#pragma unroll
                for (int j = 0; j < 2; ++j) {
                    int c = tid + j * 256;
                    int row = c >> 2, sp = c & 3;
                    GL_LDS16(Ab + (size_t)(by * 128 + row) * K + kt + SWZ4(row, sp),
                             (char*)&sA[nxt][0] + c * 16);
                }
            }
#pragma unroll
            for (int j = 0; j < BCH; ++j) {
                int c = tid + j * 256;
                int row = c >> 2, sp = c & 3;
                GL_LDS16(Bt + (size_t)(bx * BN + row) * K + kt + SWZ4(row, sp),
                         (char*)&sB[nxt][0] + c * 16);
            }
        }

        bf16x8 af[4], bfr[NJ];
#pragma unroll
        for (int i = 0; i < 4; ++i) {
            int row = wr * 64 + i * 16 + l15;
            af[i] = *(const bf16x8*)(&sA[cur][row * 32 + SWZ4(row, g)]);
        }
#pragma unroll
        for (int j = 0; j < NJ; ++j) {
            int row = wc * (BN / 2) + j * 16 + l15;
            bfr[j] = *(const bf16x8*)(&sB[cur][row * 32 + SWZ4(row, g)]);
        }
#pragma unroll
        for (int i = 0; i < 4; ++i)
#pragma unroll
            for (int j = 0; j < NJ; ++j)
                acc[i][j] = __builtin_amdgcn_mfma_f32_16x16x32_bf16(af[i], bfr[j], acc[i][j], 0, 0, 0);

        if (pre) {
            if constexpr (A_F32) {
#pragma unroll
                for (int j = 0; j < 2; ++j) {
                    int c = tid + j * 256;
                    int row = c >> 2, s = c & 3;
                    bf16x8 vv;
                    vv[0] = f2bf(ra[j][0].x); vv[1] = f2bf(ra[j][0].y);
                    vv[2] = f2bf(ra[j][0].z); vv[3] = f2bf(ra[j][0].w);
                    vv[4] = f2bf(ra[j][1].x); vv[5] = f2bf(ra[j][1].y);
                    vv[6] = f2bf(ra[j][1].z); vv[7] = f2bf(ra[j][1].w);
                    *(bf16x8*)(&sA[nxt][row * 32 + SWZ4(row, s)]) = vv;
                }
            }
        }
    }

#pragma unroll
    for (int i = 0; i < 4; ++i)
#pragma unroll
        for (int j = 0; j < NJ; ++j)
#pragma unroll
            for (int r = 0; r < 4; ++r) {
                int row = by * 128 + wr * 64 + i * 16 + g * 4 + r;
                int col = bx * BN + wc * (BN / 2) + j * 16 + l15;
                if constexpr (C_F32)
                    ((float*)Cv)[(size_t)row * DDIM + col] = acc[i][j][r];
                else
                    ((short*)Cv)[(size_t)row * DDIM + col] = f2bf(acc[i][j][r]);
            }
}

// ---------------------------------------------------------------------------
// Flash attention per (b, h, 64-q-rows). 4 waves x 16 q-rows, KV tiles of 64.
// DOUBLE-BUFFERED K/V staging: issue next-tile loads (K: global_load_lds,
// V: global->reg) BEFORE computing current tile; scatter V regs after compute;
// ONE barrier per tile. Load latency hides under QK^T/softmax/PV.
__global__ __launch_bounds__(256) void attn(const short* __restrict__ q,
                                            const short* __restrict__ k,
                                            const short* __restrict__ v,
                                            const int* __restrict__ vlens,
                                            short* __restrict__ att) {
    const int blk = blockIdx.x;            // 1024
    const int qt = blk >> 6;               // 0..15
    const int hb = blk & 63;
    const int bb = hb & 3;                 // batch varies fastest
    const int h  = hb >> 2;

    const int tid = threadIdx.x;
    const int lane = tid & 63, wid = tid >> 6;
    const int g = lane >> 4, l15 = lane & 15;
    const int vlen = vlens[bb];

    __shared__ short sK[2][64 * 64];       // dbuf, [key][d-slots] swz by key&7
    __shared__ short sV[2][64 * 64];       // dbuf, [e][key-slots] swz by e&7
    __shared__ short sP[4][16 * 64];       // per-wave [q][key-slots] swz by q&7

    const int srow = qt * 64 + wid * 16 + l15;
    const short* qrow = q + ((size_t)(bb * SS + srow)) * DDIM + h * 64;
    bf16x8 qf[2];
    qf[0] = *(const bf16x8*)(qrow + g * 8);
    qf[1] = *(const bf16x8*)(qrow + 32 + g * 8);

    float m_run[4], l_run[4];
#pragma unroll
    for (int r = 0; r < 4; ++r) { m_run[r] = -1e30f; l_run[r] = 0.0f; }
    f32x4 oacc[4] = {};

    // per-thread staging coords (two 16B chunks: c and c+256)
    const int key0 = tid >> 3,          sp0 = tid & 7;          // chunk c=tid
    const int key1 = (tid + 256) >> 3,  sp1 = tid & 7;          // chunk c=tid+256
    const int d0v0 = (tid & 7) << 3,    d0v1 = (tid & 7) << 3;

    const int ntiles = (vlen + 63) >> 6;

    // ---- prologue: stage tile 0 into buf 0 ----
    {
        GL_LDS16(k + ((size_t)(bb * SS + key0)) * DDIM + h * 64 + ((sp0 ^ (key0 & 7)) << 3),
                 (char*)&sK[0][0] + tid * 16);
        GL_LDS16(k + ((size_t)(bb * SS + key1)) * DDIM + h * 64 + ((sp1 ^ (key1 & 7)) << 3),
                 (char*)&sK[0][0] + (tid + 256) * 16);
        bf16x8 v0 = *(const bf16x8*)(v + ((size_t)(bb * SS + key0)) * DDIM + h * 64 + d0v0);
        bf16x8 v1 = *(const bf16x8*)(v + ((size_t)(bb * SS + key1)) * DDIM + h * 64 + d0v1);
#pragma unroll
        for (int e = 0; e < 8; ++e) {
            int e0 = d0v0 + e;
            sV[0][e0 * 64 + (((key0 >> 3) ^ (e0 & 7)) << 3) + (key0 & 7)] = v0[e];
            int e1 = d0v1 + e;
            sV[0][e1 * 64 + (((key1 >> 3) ^ (e1 & 7)) << 3) + (key1 & 7)] = v1[e];
        }
    }
    __syncthreads();

    for (int t = 0; t < ntiles; ++t) {
        const int cur = t & 1, nxt = cur ^ 1;
        const int kb = t * 64;
        const bool pre = (t + 1 < ntiles);

        // ---- issue next-tile staging before compute ----
        bf16x8 vr0, vr1;
        if (pre) {
            const int kb2 = kb + 64;
            GL_LDS16(k + ((size_t)(bb * SS + kb2 + key0)) * DDIM + h * 64 + ((sp0 ^ (key0 & 7)) << 3),
                     (char*)&sK[nxt][0] + tid * 16);
            GL_LDS16(k + ((size_t)(bb * SS + kb2 + key1)) * DDIM + h * 64 + ((sp1 ^ (key1 & 7)) << 3),
                     (char*)&sK[nxt][0] + (tid + 256) * 16);
            vr0 = *(const bf16x8*)(v + ((size_t)(bb * SS + kb2 + key0)) * DDIM + h * 64 + d0v0);
            vr1 = *(const bf16x8*)(v + ((size_t)(bb * SS + kb2 + key1)) * DDIM + h * 64 + d0v1);
        }

        // ---- QK^T on buf[cur] ----
        f32x4 sacc[4] = {};
#pragma unroll
        for (int kg = 0; kg < 4; ++kg) {
            int row = kg * 16 + l15;
#pragma unroll
            for (int kh = 0; kh < 2; ++kh) {
                int s = kh * 4 + g;
                bf16x8 kf = *(const bf16x8*)(&sK[cur][row * 64 + ((s ^ (row & 7)) << 3)]);
                sacc[kg] = __builtin_amdgcn_mfma_f32_16x16x32_bf16(qf[kh], kf, sacc[kg], 0, 0, 0);
            }
        }

        // ---- online softmax ----
        float f[4];
#pragma unroll
        for (int r = 0; r < 4; ++r) {
            float s[4];
#pragma unroll
            for (int kg = 0; kg < 4; ++kg) {
                s[kg] = sacc[kg][r] * 0.125f;
                if (kb + kg * 16 + l15 >= vlen) s[kg] = -1e30f;
            }
            float tmax = fmaxf(fmaxf(s[0], s[1]), fmaxf(s[2], s[3]));
#pragma unroll
            for (int off = 1; off < 16; off <<= 1)
                tmax = fmaxf(tmax, __shfl_xor(tmax, off));
            float mn = fmaxf(m_run[r], tmax);
            f[r] = __expf(m_run[r] - mn);
            m_run[r] = mn;
            float p[4], rs = 0.0f;
#pragma unroll
            for (int kg = 0; kg < 4; ++kg) { p[kg] = __expf(s[kg] - mn); rs += p[kg]; }
#pragma unroll
            for (int off = 1; off < 16; off <<= 1)
                rs += __shfl_xor(rs, off);
            l_run[r] = l_run[r] * f[r] + rs;
            const int srw = g * 4 + r;
#pragma unroll
            for (int kg = 0; kg < 4; ++kg) {
                int col = kg * 16 + l15;
                sP[wid][srw * 64 + (((col >> 3) ^ (srw & 7)) << 3) + (col & 7)] = f2bf(p[kg]);
            }
        }

        // ---- PV on buf[cur] ----
        bf16x8 pf[2];
#pragma unroll
        for (int kh = 0; kh < 2; ++kh) {
            int s = kh * 4 + g;
            pf[kh] = *(const bf16x8*)(&sP[wid][l15 * 64 + ((s ^ (l15 & 7)) << 3)]);
        }
#pragma unroll
        for (int n = 0; n < 4; ++n) {
#pragma unroll
            for (int r = 0; r < 4; ++r) oacc[n][r] *= f[r];
            const int e = n * 16 + l15;
#pragma unroll
            for (int kh = 0; kh < 2; ++kh) {
                int s = kh * 4 + g;
                bf16x8 vf = *(const bf16x8*)(&sV[cur][e * 64 + ((s ^ (e & 7)) << 3)]);
                oacc[n] = __builtin_amdgcn_mfma_f32_16x16x32_bf16(pf[kh], vf, oacc[n], 0, 0, 0);
            }
        }

        // ---- late write of prefetched V into buf[nxt] ----
        if (pre) {
#pragma unroll
            for (int e = 0; e < 8; ++e) {
                int e0 = d0v0 + e;
                sV[nxt][e0 * 64 + (((key0 >> 3) ^ (e0 & 7)) << 3) + (key0 & 7)] = vr0[e];
                int e1 = d0v1 + e;
                sV[nxt][e1 * 64 + (((key1 >> 3) ^ (e1 & 7)) << 3) + (key1 & 7)] = vr1[e];
            }
        }
        __syncthreads();   // one barrier per tile: buf[nxt] fully staged
    }

    // write head-interleaved: att[bb][s][e*H + h]
#pragma unroll
    for (int n = 0; n < 4; ++n)
#pragma unroll
        for (int r = 0; r < 4; ++r) {
            float o = oacc[n][r] / l_run[r];
            int sg = qt * 64 + wid * 16 + g * 4 + r;
            int e = n * 16 + l15;
            att[((size_t)(bb * SS + sg)) * DDIM + e * HH + h] = f2bf(o);
        }
}

extern "C" void kernel_launch(void* const* d_in, const int* in_sizes, int n_in,
                              void* d_out, int out_size, void* d_ws, size_t ws_size,
                              hipStream_t stream) {
    const float* queries = (const float*)d_in[0];
    const float* keys    = (const float*)d_in[1];
    const float* values  = (const float*)d_in[2];
    const int*   vlens   = (const int*)d_in[3];
    const float* Wq      = (const float*)d_in[4];
    const float* Wk      = (const float*)d_in[5];
    const float* Wv      = (const float*)d_in[6];
    const float* Wo      = (const float*)d_in[7];
    float* out = (float*)d_out;

    short* ws = (short*)d_ws;
    const size_t sz = (size_t)MROWS * DDIM;   // 4M elems
    short* q_ws   = ws;
    short* k_ws   = ws + sz;
    short* v_ws   = ws + 2 * sz;
    short* att_ws = ws + 3 * sz;
    short* wt3  = att_ws;
    short* wt_o = q_ws;

    dim3 tgrid3(16, 16, 3);
    dim3 tgrid1(16, 16, 1);

    const bool big = ws_size >= (size_t)7 * sz * sizeof(short);   // 56 MB
    if (big) {
        short* qb = ws + 4 * sz;
        short* kb = ws + 5 * sz;
        short* vb = ws + 6 * sz;
        cvtA3<<<dim3(2048, 3), 256, 0, stream>>>(queries, keys, values, qb, vlens);
        transposeW3<<<tgrid3, 256, 0, stream>>>(Wq, Wk, Wv, wt3);
        gemm<false, false, 128, true><<<dim3(768), 256, 0, stream>>>(
            qb, kb, vb, wt3, q_ws, k_ws, v_ws, vlens);
    } else {
        transposeW3<<<tgrid3, 256, 0, stream>>>(Wq, Wk, Wv, wt3);
        gemm<true, false, 128, true><<<dim3(768), 256, 0, stream>>>(
            queries, keys, values, wt3, q_ws, k_ws, v_ws, vlens);
    }

    attn<<<dim3(1024), 256, 0, stream>>>(q_ws, k_ws, v_ws, vlens, att_ws);

    transposeW3<<<tgrid1, 256, 0, stream>>>(Wo, Wo, Wo, wt_o);
    gemm<false, true, 64, false><<<dim3(512), 256, 0, stream>>>(
        att_ws, att_ws, att_ws, wt_o, out, out, out, vlens);
}

// Round 11
// 111.879 us; speedup vs baseline: 1.3350x; 1.1669x over previous
//
#include <hip/hip_runtime.h>
#include <hip/hip_bf16.h>

#define BB 4
#define SS 1024
#define DDIM 1024
#define HH 16
#define MROWS (BB * SS)

typedef __attribute__((ext_vector_type(8))) short bf16x8;
typedef __attribute__((ext_vector_type(4))) float f32x4;

static __device__ __forceinline__ short f2bf(float x) {
    union { __hip_bfloat16 h; short s; } u;
    u.h = __float2bfloat16(x);
    return u.s;
}

#define GL_LDS16(gp, lp)                                                      \
    __builtin_amdgcn_global_load_lds(                                         \
        (const __attribute__((address_space(1))) void*)(gp),                  \
        (__attribute__((address_space(3))) void*)(lp), 16, 0, 0)

// BK=32 swizzle: physical 16B slot = s ^ ((row>>1)&3).
#define SWZ4(row, s) ((((s) ^ (((row) >> 1) & 3))) << 3)

// ---------------------------------------------------------------------------
// f32 [MROWS,DDIM] -> bf16, 3 tensors (z). Skips K/V rows >= vlen (2-row grain).
__global__ __launch_bounds__(256) void cvtA3(const float* __restrict__ X0,
                                             const float* __restrict__ X1,
                                             const float* __restrict__ X2,
                                             short* __restrict__ dst,
                                             const int* __restrict__ vlens) {
    const int z = blockIdx.y;
    const int blk = blockIdx.x;          // 2048 blocks x 2048 elems (2 rows)
    const int row0 = blk << 1;
    if (z >= 1) {
        const int bb = row0 >> 10;
        if ((row0 & 1023) >= vlens[bb]) return;
    }
    const float* X = (z == 0) ? X0 : (z == 1) ? X1 : X2;
    short* D = dst + (size_t)z * MROWS * DDIM;
    const size_t base = (size_t)blk * 2048 + threadIdx.x * 8;
    const float4 x0 = ((const float4*)(X + base))[0];
    const float4 x1 = ((const float4*)(X + base))[1];
    bf16x8 vv;
    vv[0] = f2bf(x0.x); vv[1] = f2bf(x0.y); vv[2] = f2bf(x0.z); vv[3] = f2bf(x0.w);
    vv[4] = f2bf(x1.x); vv[5] = f2bf(x1.y); vv[6] = f2bf(x1.z); vv[7] = f2bf(x1.w);
    *(bf16x8*)(D + base) = vv;
}

// ---------------------------------------------------------------------------
// Weight transpose+convert: W [K,N] f32 -> Wt [N,K] bf16. 64x64 tiles.
__global__ __launch_bounds__(256) void transposeW3(const float* __restrict__ W0,
                                                   const float* __restrict__ W1,
                                                   const float* __restrict__ W2,
                                                   short* __restrict__ Wt) {
    const int z = blockIdx.z;
    const float* W = (z == 0) ? W0 : (z == 1) ? W1 : W2;
    short* dst = Wt + (size_t)z * DDIM * DDIM;
    __shared__ short sT[64][72];
    const int t = threadIdx.x;
    const int k0 = blockIdx.y * 64, n0 = blockIdx.x * 64;
    {
        int r = t >> 2, cq = (t & 3) << 4;
        const float* p = W + (size_t)(k0 + r) * DDIM + n0 + cq;
        float4 a = ((const float4*)p)[0], b = ((const float4*)p)[1];
        float4 c = ((const float4*)p)[2], d = ((const float4*)p)[3];
        short* dp = &sT[r][cq];
        dp[0]  = f2bf(a.x); dp[1]  = f2bf(a.y); dp[2]  = f2bf(a.z); dp[3]  = f2bf(a.w);
        dp[4]  = f2bf(b.x); dp[5]  = f2bf(b.y); dp[6]  = f2bf(b.z); dp[7]  = f2bf(b.w);
        dp[8]  = f2bf(c.x); dp[9]  = f2bf(c.y); dp[10] = f2bf(c.z); dp[11] = f2bf(c.w);
        dp[12] = f2bf(d.x); dp[13] = f2bf(d.y); dp[14] = f2bf(d.z); dp[15] = f2bf(d.w);
    }
    __syncthreads();
    {
        int n = t >> 2, kq = (t & 3) << 4;
        bf16x8 o0, o1;
#pragma unroll
        for (int j = 0; j < 8; ++j) o0[j] = sT[kq + j][n];
#pragma unroll
        for (int j = 0; j < 8; ++j) o1[j] = sT[kq + 8 + j][n];
        short* q = dst + (size_t)(n0 + n) * DDIM + k0 + kq;
        *(bf16x8*)q = o0;
        *(bf16x8*)(q + 8) = o1;
    }
}

// ---------------------------------------------------------------------------
// V [b][s][h*64+e] bf16 -> vT [b][h][e][s] bf16. 64x64 tiles, vlen-skipped.
__global__ __launch_bounds__(256) void transposeV(const short* __restrict__ v,
                                                  short* __restrict__ vT,
                                                  const int* __restrict__ vlens) {
    const int st = blockIdx.x, h = blockIdx.y, bb = blockIdx.z;
    if (st * 64 >= vlens[bb]) return;
    __shared__ short sT[64][72];
    const int t = threadIdx.x;
#pragma unroll
    for (int j = 0; j < 2; ++j) {
        int c = t + j * 256;
        int sr = c >> 3, co = (c & 7) << 3;
        *(bf16x8*)(&sT[sr][co]) =
            *(const bf16x8*)(v + (size_t)(bb * SS + st * 64 + sr) * DDIM + h * 64 + co);
    }
    __syncthreads();
    {
        int e = t >> 2, sq = (t & 3) << 4;
        bf16x8 o0, o1;
#pragma unroll
        for (int j = 0; j < 8; ++j) o0[j] = sT[sq + j][e];
#pragma unroll
        for (int j = 0; j < 8; ++j) o1[j] = sT[sq + 8 + j][e];
        short* dst = vT + ((size_t)(bb * HH + h) * 64 + e) * SS + st * 64 + sq;
        *(bf16x8*)dst = o0;
        *(bf16x8*)(dst + 8) = o1;
    }
}

// ---------------------------------------------------------------------------
// C[z][M,N] = A[z][M,K] @ Bt[z][N,K]^T, up to 3 fused problems.
template<bool A_F32, bool C_F32, int BN, bool SKIP>
__global__ __launch_bounds__(256) void gemm(const void* __restrict__ A0v,
                                            const void* __restrict__ A1v,
                                            const void* __restrict__ A2v,
                                            const short* __restrict__ BtBase,
                                            void* __restrict__ C0v,
                                            void* __restrict__ C1v,
                                            void* __restrict__ C2v,
                                            const int* __restrict__ vlens) {
    constexpr int NJ  = BN / 32;
    constexpr int NBX = DDIM / BN;
    constexpr int NPB = 32 * NBX;
    constexpr int BCH = BN / 64;

    __shared__ short sA[2][128 * 32];
    __shared__ short sB[2][BN * 32];

    const int tid = threadIdx.x;
    const int lane = tid & 63, wid = tid >> 6;
    const int wr = wid >> 1, wc = wid & 1;
    const int g = lane >> 4, l15 = lane & 15;

    const int blk = blockIdx.x;
    const int z = blk / NPB;
    const int inner = blk % NPB;
    const int xcd = inner & 7, ii = inner >> 3;
    const int by = xcd * 4 + ii / NBX;
    const int bx = ii % NBX;

    if constexpr (SKIP) {
        if (z >= 1 && ((by & 7) << 7) >= vlens[by >> 3]) return;
    }

    const void* Av = (z == 0) ? A0v : (z == 1) ? A1v : A2v;
    const short* Bt = BtBase + (size_t)z * DDIM * DDIM;
    void* Cv = (z == 0) ? C0v : (z == 1) ? C1v : C2v;
    const float* Af = (const float*)Av;
    const short* Ab = (const short*)Av;
    const int K = DDIM;

    f32x4 acc[4][NJ] = {};
    const int nkt = K >> 5;

    if constexpr (A_F32) {
#pragma unroll
        for (int j = 0; j < 2; ++j) {
            int c = tid + j * 256;
            int row = c >> 2, s = c & 3;
            const float* p = Af + (size_t)(by * 128 + row) * K + s * 8;
            float4 x0 = ((const float4*)p)[0];
            float4 x1 = ((const float4*)p)[1];
            bf16x8 vv;
            vv[0] = f2bf(x0.x); vv[1] = f2bf(x0.y); vv[2] = f2bf(x0.z); vv[3] = f2bf(x0.w);
            vv[4] = f2bf(x1.x); vv[5] = f2bf(x1.y); vv[6] = f2bf(x1.z); vv[7] = f2bf(x1.w);
            *(bf16x8*)(&sA[0][row * 32 + SWZ4(row, s)]) = vv;
        }
    } else {
#pragma unroll
        for (int j = 0; j < 2; ++j) {
            int c = tid + j * 256;
            int row = c >> 2, sp = c & 3;
            GL_LDS16(Ab + (size_t)(by * 128 + row) * K + SWZ4(row, sp),
                     (char*)&sA[0][0] + c * 16);
        }
    }
#pragma unroll
    for (int j = 0; j < BCH; ++j) {
        int c = tid + j * 256;
        int row = c >> 2, sp = c & 3;
        GL_LDS16(Bt + (size_t)(bx * BN + row) * K + SWZ4(row, sp),
                 (char*)&sB[0][0] + c * 16);
    }

    for (int t = 0; t < nkt; ++t) {
        const int cur = t & 1, nxt = cur ^ 1;
        __syncthreads();

        const bool pre = (t + 1 < nkt);
        float4 ra[2][2];
        if (pre) {
            const int kt = (t + 1) << 5;
            if constexpr (A_F32) {
#pragma unroll
                for (int j = 0; j < 2; ++j) {
                    int c = tid + j * 256;
                    int row = c >> 2, s = c & 3;
                    const float* p = Af + (size_t)(by * 128 + row) * K + kt + s * 8;
                    ra[j][0] = ((const float4*)p)[0];
                    ra[j][1] = ((const float4*)p)[1];
                }
            } else {
#pragma unroll
                for (int j = 0; j < 2; ++j) {
                    int c = tid + j * 256;
                    int row = c >> 2, sp = c & 3;
                    GL_LDS16(Ab + (size_t)(by * 128 + row) * K + kt + SWZ4(row, sp),
                             (char*)&sA[nxt][0] + c * 16);
                }
            }
#pragma unroll
            for (int j = 0; j < BCH; ++j) {
                int c = tid + j * 256;
                int row = c >> 2, sp = c & 3;
                GL_LDS16(Bt + (size_t)(bx * BN + row) * K + kt + SWZ4(row, sp),
                         (char*)&sB[nxt][0] + c * 16);
            }
        }

        bf16x8 af[4], bfr[NJ];
#pragma unroll
        for (int i = 0; i < 4; ++i) {
            int row = wr * 64 + i * 16 + l15;
            af[i] = *(const bf16x8*)(&sA[cur][row * 32 + SWZ4(row, g)]);
        }
#pragma unroll
        for (int j = 0; j < NJ; ++j) {
            int row = wc * (BN / 2) + j * 16 + l15;
            bfr[j] = *(const bf16x8*)(&sB[cur][row * 32 + SWZ4(row, g)]);
        }
#pragma unroll
        for (int i = 0; i < 4; ++i)
#pragma unroll
            for (int j = 0; j < NJ; ++j)
                acc[i][j] = __builtin_amdgcn_mfma_f32_16x16x32_bf16(af[i], bfr[j], acc[i][j], 0, 0, 0);

        if (pre) {
            if constexpr (A_F32) {
#pragma unroll
                for (int j = 0; j < 2; ++j) {
                    int c = tid + j * 256;
                    int row = c >> 2, s = c & 3;
                    bf16x8 vv;
                    vv[0] = f2bf(ra[j][0].x); vv[1] = f2bf(ra[j][0].y);
                    vv[2] = f2bf(ra[j][0].z); vv[3] = f2bf(ra[j][0].w);
                    vv[4] = f2bf(ra[j][1].x); vv[5] = f2bf(ra[j][1].y);
                    vv[6] = f2bf(ra[j][1].z); vv[7] = f2bf(ra[j][1].w);
                    *(bf16x8*)(&sA[nxt][row * 32 + SWZ4(row, s)]) = vv;
                }
            }
        }
    }

#pragma unroll
    for (int i = 0; i < 4; ++i)
#pragma unroll
        for (int j = 0; j < NJ; ++j)
#pragma unroll
            for (int r = 0; r < 4; ++r) {
                int row = by * 128 + wr * 64 + i * 16 + g * 4 + r;
                int col = bx * BN + wc * (BN / 2) + j * 16 + l15;
                if constexpr (C_F32)
                    ((float*)Cv)[(size_t)row * DDIM + col] = acc[i][j][r];
                else
                    ((short*)Cv)[(size_t)row * DDIM + col] = f2bf(acc[i][j][r]);
            }
}

// ---------------------------------------------------------------------------
// Flash attention per (b, h, 64-q-rows). 4 waves x 16 q-rows, KV tiles of 64.
// Fixed-offset softmax (m=0, exact by shift-invariance; scores bounded, clamped
// at 60): p=exp(s), lane-local l accumulation, ONE cross-lane reduce at end.
// TRV: V pre-transposed [b][h][e][s] -> staged via global_load_lds like K.
template<bool TRV>
__global__ __launch_bounds__(256) void attn(const short* __restrict__ q,
                                            const short* __restrict__ k,
                                            const short* __restrict__ v,
                                            const int* __restrict__ vlens,
                                            short* __restrict__ att) {
    const int blk = blockIdx.x;            // 1024
    const int qt = blk >> 6;
    const int hb = blk & 63;
    const int bb = hb & 3;                 // batch varies fastest
    const int h  = hb >> 2;

    const int tid = threadIdx.x;
    const int lane = tid & 63, wid = tid >> 6;
    const int g = lane >> 4, l15 = lane & 15;
    const int vlen = vlens[bb];

    __shared__ short sK[2][64 * 64];       // [key][d-slots] swz by key&7
    __shared__ short sV[2][64 * 64];       // [e][key-slots] swz by e&7
    __shared__ short sP[4][16 * 64];       // per-wave [q][key-slots]

    const int srow = qt * 64 + wid * 16 + l15;
    const short* qrow = q + ((size_t)(bb * SS + srow)) * DDIM + h * 64;
    bf16x8 qf[2];
    qf[0] = *(const bf16x8*)(qrow + g * 8);
    qf[1] = *(const bf16x8*)(qrow + 32 + g * 8);

    float lsum[4] = {0.f, 0.f, 0.f, 0.f};
    f32x4 oacc[4] = {};

    const int key0 = tid >> 3, key1 = (tid + 256) >> 3, sp = tid & 7;
    const int d0 = (tid & 7) << 3;
    const short* vTb = v + ((size_t)(bb * HH + h) * 64) * SS;   // TRV base

    const int ntiles = (vlen + 63) >> 6;

    // ---- prologue: stage tile 0 into buf 0 ----
    {
        GL_LDS16(k + ((size_t)(bb * SS + key0)) * DDIM + h * 64 + ((sp ^ (key0 & 7)) << 3),
                 (char*)&sK[0][0] + tid * 16);
        GL_LDS16(k + ((size_t)(bb * SS + key1)) * DDIM + h * 64 + ((sp ^ (key1 & 7)) << 3),
                 (char*)&sK[0][0] + (tid + 256) * 16);
        if constexpr (TRV) {
            GL_LDS16(vTb + (size_t)key0 * SS + ((sp ^ (key0 & 7)) << 3),
                     (char*)&sV[0][0] + tid * 16);
            GL_LDS16(vTb + (size_t)key1 * SS + ((sp ^ (key1 & 7)) << 3),
                     (char*)&sV[0][0] + (tid + 256) * 16);
        } else {
            bf16x8 v0 = *(const bf16x8*)(v + ((size_t)(bb * SS + key0)) * DDIM + h * 64 + d0);
            bf16x8 v1 = *(const bf16x8*)(v + ((size_t)(bb * SS + key1)) * DDIM + h * 64 + d0);
#pragma unroll
            for (int e = 0; e < 8; ++e) {
                int e0 = d0 + e;
                sV[0][e0 * 64 + (((key0 >> 3) ^ (e0 & 7)) << 3) + (key0 & 7)] = v0[e];
                sV[0][e0 * 64 + (((key1 >> 3) ^ (e0 & 7)) << 3) + (key1 & 7)] = v1[e];
            }
        }
    }
    __syncthreads();

    for (int t = 0; t < ntiles; ++t) {
        const int cur = t & 1, nxt = cur ^ 1;
        const int kb = t * 64;
        const bool pre = (t + 1 < ntiles);

        // ---- issue next-tile staging before compute ----
        bf16x8 vr0, vr1;
        if (pre) {
            const int kb2 = kb + 64;
            GL_LDS16(k + ((size_t)(bb * SS + kb2 + key0)) * DDIM + h * 64 + ((sp ^ (key0 & 7)) << 3),
                     (char*)&sK[nxt][0] + tid * 16);
            GL_LDS16(k + ((size_t)(bb * SS + kb2 + key1)) * DDIM + h * 64 + ((sp ^ (key1 & 7)) << 3),
                     (char*)&sK[nxt][0] + (tid + 256) * 16);
            if constexpr (TRV) {
                GL_LDS16(vTb + (size_t)key0 * SS + kb2 + ((sp ^ (key0 & 7)) << 3),
                         (char*)&sV[nxt][0] + tid * 16);
                GL_LDS16(vTb + (size_t)key1 * SS + kb2 + ((sp ^ (key1 & 7)) << 3),
                         (char*)&sV[nxt][0] + (tid + 256) * 16);
            } else {
                vr0 = *(const bf16x8*)(v + ((size_t)(bb * SS + kb2 + key0)) * DDIM + h * 64 + d0);
                vr1 = *(const bf16x8*)(v + ((size_t)(bb * SS + kb2 + key1)) * DDIM + h * 64 + d0);
            }
        }

        // ---- QK^T on buf[cur] ----
        f32x4 sacc[4] = {};
#pragma unroll
        for (int kg = 0; kg < 4; ++kg) {
            int row = kg * 16 + l15;
#pragma unroll
            for (int kh = 0; kh < 2; ++kh) {
                int s = kh * 4 + g;
                bf16x8 kf = *(const bf16x8*)(&sK[cur][row * 64 + ((s ^ (row & 7)) << 3)]);
                sacc[kg] = __builtin_amdgcn_mfma_f32_16x16x32_bf16(qf[kh], kf, sacc[kg], 0, 0, 0);
            }
        }

        // ---- softmax, fixed offset (no cross-lane ops) ----
#pragma unroll
        for (int r = 0; r < 4; ++r) {
            float p[4], ls = 0.f;
#pragma unroll
            for (int kg = 0; kg < 4; ++kg) {
                float s = fminf(sacc[kg][r] * 0.125f, 60.0f);
                if (kb + kg * 16 + l15 >= vlen) s = -1e30f;
                p[kg] = __expf(s);
                ls += p[kg];
            }
            lsum[r] += ls;
            const int srw = g * 4 + r;
#pragma unroll
            for (int kg = 0; kg < 4; ++kg) {
                int col = kg * 16 + l15;
                sP[wid][srw * 64 + (((col >> 3) ^ (srw & 7)) << 3) + (col & 7)] = f2bf(p[kg]);
            }
        }

        // ---- PV on buf[cur] (no rescale) ----
        bf16x8 pf[2];
#pragma unroll
        for (int kh = 0; kh < 2; ++kh) {
            int s = kh * 4 + g;
            pf[kh] = *(const bf16x8*)(&sP[wid][l15 * 64 + ((s ^ (l15 & 7)) << 3)]);
        }
#pragma unroll
        for (int n = 0; n < 4; ++n) {
            const int e = n * 16 + l15;
#pragma unroll
            for (int kh = 0; kh < 2; ++kh) {
                int s = kh * 4 + g;
                bf16x8 vf = *(const bf16x8*)(&sV[cur][e * 64 + ((s ^ (e & 7)) << 3)]);
                oacc[n] = __builtin_amdgcn_mfma_f32_16x16x32_bf16(pf[kh], vf, oacc[n], 0, 0, 0);
            }
        }

        // ---- late write of prefetched V (non-TRV only) ----
        if constexpr (!TRV) {
            if (pre) {
#pragma unroll
                for (int e = 0; e < 8; ++e) {
                    int e0 = d0 + e;
                    sV[nxt][e0 * 64 + (((key0 >> 3) ^ (e0 & 7)) << 3) + (key0 & 7)] = vr0[e];
                    sV[nxt][e0 * 64 + (((key1 >> 3) ^ (e0 & 7)) << 3) + (key1 & 7)] = vr1[e];
                }
            }
        }
        __syncthreads();
    }

    // ---- epilogue: single 16-lane reduction of l per q-row ----
#pragma unroll
    for (int r = 0; r < 4; ++r) {
        float rs = lsum[r];
#pragma unroll
        for (int off = 1; off < 16; off <<= 1)
            rs += __shfl_xor(rs, off);
        lsum[r] = rs;
    }

    // write head-interleaved: att[bb][s][e*H + h]
#pragma unroll
    for (int n = 0; n < 4; ++n)
#pragma unroll
        for (int r = 0; r < 4; ++r) {
            float o = oacc[n][r] / lsum[r];
            int sg = qt * 64 + wid * 16 + g * 4 + r;
            int e = n * 16 + l15;
            att[((size_t)(bb * SS + sg)) * DDIM + e * HH + h] = f2bf(o);
        }
}

extern "C" void kernel_launch(void* const* d_in, const int* in_sizes, int n_in,
                              void* d_out, int out_size, void* d_ws, size_t ws_size,
                              hipStream_t stream) {
    const float* queries = (const float*)d_in[0];
    const float* keys    = (const float*)d_in[1];
    const float* values  = (const float*)d_in[2];
    const int*   vlens   = (const int*)d_in[3];
    const float* Wq      = (const float*)d_in[4];
    const float* Wk      = (const float*)d_in[5];
    const float* Wv      = (const float*)d_in[6];
    const float* Wo      = (const float*)d_in[7];
    float* out = (float*)d_out;

    short* ws = (short*)d_ws;
    const size_t sz = (size_t)MROWS * DDIM;   // 4M elems, 8MB per region
    short* q_ws   = ws;
    short* k_ws   = ws + sz;
    short* v_ws   = ws + 2 * sz;
    short* att_ws = ws + 3 * sz;
    short* wt3  = att_ws;                     // dead until attn writes
    short* wt_o = q_ws;                       // dead after attn reads q

    dim3 tgrid3(16, 16, 3);
    dim3 tgrid1(16, 16, 1);
    dim3 vgrid(16, 16, 4);

    const size_t regionB = sz * sizeof(short);
    const bool big = ws_size >= 7 * regionB;   // cvt buffers + vT
    const bool mid = ws_size >= 5 * regionB;   // vT only

    if (big) {
        short* qb = ws + 4 * sz;
        short* kb = ws + 5 * sz;
        short* vb = ws + 6 * sz;
        cvtA3<<<dim3(2048, 3), 256, 0, stream>>>(queries, keys, values, qb, vlens);
        transposeW3<<<tgrid3, 256, 0, stream>>>(Wq, Wk, Wv, wt3);
        gemm<false, false, 128, true><<<dim3(768), 256, 0, stream>>>(
            qb, kb, vb, wt3, q_ws, k_ws, v_ws, vlens);
        transposeV<<<vgrid, 256, 0, stream>>>(v_ws, qb, vlens);   // qb dead now
        attn<true><<<dim3(1024), 256, 0, stream>>>(q_ws, k_ws, qb, vlens, att_ws);
    } else if (mid) {
        short* vT = ws + 4 * sz;
        transposeW3<<<tgrid3, 256, 0, stream>>>(Wq, Wk, Wv, wt3);
        gemm<true, false, 128, true><<<dim3(768), 256, 0, stream>>>(
            queries, keys, values, wt3, q_ws, k_ws, v_ws, vlens);
        transposeV<<<vgrid, 256, 0, stream>>>(v_ws, vT, vlens);
        attn<true><<<dim3(1024), 256, 0, stream>>>(q_ws, k_ws, vT, vlens, att_ws);
    } else {
        transposeW3<<<tgrid3, 256, 0, stream>>>(Wq, Wk, Wv, wt3);
        gemm<true, false, 128, true><<<dim3(768), 256, 0, stream>>>(
            queries, keys, values, wt3, q_ws, k_ws, v_ws, vlens);
        attn<false><<<dim3(1024), 256, 0, stream>>>(q_ws, k_ws, v_ws, vlens, att_ws);
    }

    transposeW3<<<tgrid1, 256, 0, stream>>>(Wo, Wo, Wo, wt_o);
    gemm<false, true, 64, false><<<dim3(512), 256, 0, stream>>>(
        att_ws, att_ws, att_ws, wt_o, out, out, out, vlens);
}

// Round 12
// 98.812 us; speedup vs baseline: 1.5115x; 1.1322x over previous
//
#include <hip/hip_runtime.h>
#include <hip/hip_bf16.h>

#define BB 4
#define SS 1024
#define DDIM 1024
#define HH 16
#define MROWS (BB * SS)

typedef __attribute__((ext_vector_type(8))) short bf16x8;
typedef __attribute__((ext_vector_type(4))) float f32x4;

static __device__ __forceinline__ short f2bf(float x) {
    union { __hip_bfloat16 h; short s; } u;
    u.h = __float2bfloat16(x);
    return u.s;
}

#define GL_LDS16(gp, lp)                                                      \
    __builtin_amdgcn_global_load_lds(                                         \
        (const __attribute__((address_space(1))) void*)(gp),                  \
        (__attribute__((address_space(3))) void*)(lp), 16, 0, 0)

// 128B-row swizzle (8 x 16B slots): physical slot = s ^ (row&7).
#define SWZ8(row, s) (((s) ^ ((row) & 7)) << 3)

// ---------------------------------------------------------------------------
// f32 [MROWS,DDIM] -> bf16, 3 tensors (z). Skips K/V rows >= vlen (2-row grain).
__global__ __launch_bounds__(256) void cvtA3(const float* __restrict__ X0,
                                             const float* __restrict__ X1,
                                             const float* __restrict__ X2,
                                             short* __restrict__ dst,
                                             const int* __restrict__ vlens) {
    const int z = blockIdx.y;
    const int blk = blockIdx.x;          // 2048 blocks x 2048 elems (2 rows)
    const int row0 = blk << 1;
    if (z >= 1) {
        const int bb = row0 >> 10;
        if ((row0 & 1023) >= vlens[bb]) return;
    }
    const float* X = (z == 0) ? X0 : (z == 1) ? X1 : X2;
    short* D = dst + (size_t)z * MROWS * DDIM;
    const size_t base = (size_t)blk * 2048 + threadIdx.x * 8;
    const float4 x0 = ((const float4*)(X + base))[0];
    const float4 x1 = ((const float4*)(X + base))[1];
    bf16x8 vv;
    vv[0] = f2bf(x0.x); vv[1] = f2bf(x0.y); vv[2] = f2bf(x0.z); vv[3] = f2bf(x0.w);
    vv[4] = f2bf(x1.x); vv[5] = f2bf(x1.y); vv[6] = f2bf(x1.z); vv[7] = f2bf(x1.w);
    *(bf16x8*)(D + base) = vv;
}

// ---------------------------------------------------------------------------
// Weight transpose+convert: W [K,N] f32 -> Wt [N,K] bf16. 64x64 tiles.
__global__ __launch_bounds__(256) void transposeW3(const float* __restrict__ W0,
                                                   const float* __restrict__ W1,
                                                   const float* __restrict__ W2,
                                                   short* __restrict__ Wt) {
    const int z = blockIdx.z;
    const float* W = (z == 0) ? W0 : (z == 1) ? W1 : W2;
    short* dst = Wt + (size_t)z * DDIM * DDIM;
    __shared__ short sT[64][72];
    const int t = threadIdx.x;
    const int k0 = blockIdx.y * 64, n0 = blockIdx.x * 64;
    {
        int r = t >> 2, cq = (t & 3) << 4;
        const float* p = W + (size_t)(k0 + r) * DDIM + n0 + cq;
        float4 a = ((const float4*)p)[0], b = ((const float4*)p)[1];
        float4 c = ((const float4*)p)[2], d = ((const float4*)p)[3];
        short* dp = &sT[r][cq];
        dp[0]  = f2bf(a.x); dp[1]  = f2bf(a.y); dp[2]  = f2bf(a.z); dp[3]  = f2bf(a.w);
        dp[4]  = f2bf(b.x); dp[5]  = f2bf(b.y); dp[6]  = f2bf(b.z); dp[7]  = f2bf(b.w);
        dp[8]  = f2bf(c.x); dp[9]  = f2bf(c.y); dp[10] = f2bf(c.z); dp[11] = f2bf(c.w);
        dp[12] = f2bf(d.x); dp[13] = f2bf(d.y); dp[14] = f2bf(d.z); dp[15] = f2bf(d.w);
    }
    __syncthreads();
    {
        int n = t >> 2, kq = (t & 3) << 4;
        bf16x8 o0, o1;
#pragma unroll
        for (int j = 0; j < 8; ++j) o0[j] = sT[kq + j][n];
#pragma unroll
        for (int j = 0; j < 8; ++j) o1[j] = sT[kq + 8 + j][n];
        short* q = dst + (size_t)(n0 + n) * DDIM + k0 + kq;
        *(bf16x8*)q = o0;
        *(bf16x8*)(q + 8) = o1;
    }
}

// ---------------------------------------------------------------------------
// V [b][s][h*64+e] bf16 -> vT [b][h][e][s] bf16. 64x64 tiles, vlen-skipped.
__global__ __launch_bounds__(256) void transposeV(const short* __restrict__ v,
                                                  short* __restrict__ vT,
                                                  const int* __restrict__ vlens) {
    const int st = blockIdx.x, h = blockIdx.y, bb = blockIdx.z;
    if (st * 64 >= vlens[bb]) return;
    __shared__ short sT[64][72];
    const int t = threadIdx.x;
#pragma unroll
    for (int j = 0; j < 2; ++j) {
        int c = t + j * 256;
        int sr = c >> 3, co = (c & 7) << 3;
        *(bf16x8*)(&sT[sr][co]) =
            *(const bf16x8*)(v + (size_t)(bb * SS + st * 64 + sr) * DDIM + h * 64 + co);
    }
    __syncthreads();
    {
        int e = t >> 2, sq = (t & 3) << 4;
        bf16x8 o0, o1;
#pragma unroll
        for (int j = 0; j < 8; ++j) o0[j] = sT[sq + j][e];
#pragma unroll
        for (int j = 0; j < 8; ++j) o1[j] = sT[sq + 8 + j][e];
        short* dst = vT + ((size_t)(bb * HH + h) * 64 + e) * SS + st * 64 + sq;
        *(bf16x8*)dst = o0;
        *(bf16x8*)(dst + 8) = o1;
    }
}

// ---------------------------------------------------------------------------
// C[z][M,N] = A[z][M,K] @ Bt[z][N,K]^T, up to 3 fused problems.
// m97 structure: BM=128, BN template, BK=64, SINGLE LDS buffer, 2 barriers
// per K-step, 32 MFMA/wave/step, pure global_load_lds staging (bf16 path),
// swizzle (s ^ (row&7))<<3 on both sides. XCD-chunked grid; vlen SKIP.
template<bool A_F32, bool C_F32, int BN, bool SKIP>
__global__ __launch_bounds__(256) void gemm(const void* __restrict__ A0v,
                                            const void* __restrict__ A1v,
                                            const void* __restrict__ A2v,
                                            const short* __restrict__ BtBase,
                                            void* __restrict__ C0v,
                                            void* __restrict__ C1v,
                                            void* __restrict__ C2v,
                                            const int* __restrict__ vlens) {
    constexpr int NJ  = BN / 32;        // acc cols per wave
    constexpr int NBX = DDIM / BN;      // col panels
    constexpr int NPB = 32 * NBX;       // blocks per problem
    constexpr int BCH = BN / 32;        // B chunks per thread (BN*8/256)

    __shared__ short sA[128 * 64];      // 16 KB
    __shared__ short sB[BN * 64];       // 16 or 8 KB

    const int tid = threadIdx.x;
    const int lane = tid & 63, wid = tid >> 6;
    const int wr = wid >> 1, wc = wid & 1;
    const int g = lane >> 4, l15 = lane & 15;

    const int blk = blockIdx.x;
    const int z = blk / NPB;
    const int inner = blk % NPB;
    const int xcd = inner & 7, ii = inner >> 3;
    const int by = xcd * 4 + ii / NBX;
    const int bx = ii % NBX;

    if constexpr (SKIP) {
        if (z >= 1 && ((by & 7) << 7) >= vlens[by >> 3]) return;
    }

    const void* Av = (z == 0) ? A0v : (z == 1) ? A1v : A2v;
    const short* Bt = BtBase + (size_t)z * DDIM * DDIM;
    void* Cv = (z == 0) ? C0v : (z == 1) ? C1v : C2v;
    const float* Af = (const float*)Av;
    const short* Ab = (const short*)Av;
    const int K = DDIM;

    f32x4 acc[4][NJ] = {};
    const int nkt = K >> 6;   // 16 K-steps of 64

    for (int t = 0; t < nkt; ++t) {
        const int kt = t << 6;
        __syncthreads();   // previous step's LDS reads complete

        // ---- stage A tile 128x64 (1024 chunks, 4 per thread) ----
        if constexpr (A_F32) {
            float4 ra[4][2];
#pragma unroll
            for (int j = 0; j < 4; ++j) {
                int c = tid + j * 256;
                int row = c >> 3, s = c & 7;
                const float* p = Af + (size_t)(by * 128 + row) * K + kt + s * 8;
                ra[j][0] = ((const float4*)p)[0];
                ra[j][1] = ((const float4*)p)[1];
            }
#pragma unroll
            for (int j = 0; j < 4; ++j) {
                int c = tid + j * 256;
                int row = c >> 3, s = c & 7;
                bf16x8 vv;
                vv[0] = f2bf(ra[j][0].x); vv[1] = f2bf(ra[j][0].y);
                vv[2] = f2bf(ra[j][0].z); vv[3] = f2bf(ra[j][0].w);
                vv[4] = f2bf(ra[j][1].x); vv[5] = f2bf(ra[j][1].y);
                vv[6] = f2bf(ra[j][1].z); vv[7] = f2bf(ra[j][1].w);
                *(bf16x8*)(&sA[row * 64 + SWZ8(row, s)]) = vv;
            }
        } else {
#pragma unroll
            for (int j = 0; j < 4; ++j) {
                int c = tid + j * 256;
                int row = c >> 3, sp = c & 7;
                GL_LDS16(Ab + (size_t)(by * 128 + row) * K + kt + SWZ8(row, sp),
                         (char*)&sA[0] + c * 16);
            }
        }
        // ---- stage B tile BNx64 ----
#pragma unroll
        for (int j = 0; j < BCH; ++j) {
            int c = tid + j * 256;
            int row = c >> 3, sp = c & 7;
            GL_LDS16(Bt + (size_t)(bx * BN + row) * K + kt + SWZ8(row, sp),
                     (char*)&sB[0] + c * 16);
        }
        __syncthreads();   // staging complete (vmcnt+lgkm drained by compiler)

        // ---- fragments + 32 MFMA ----
        bf16x8 af[4][2], bfr[NJ][2];
#pragma unroll
        for (int i = 0; i < 4; ++i) {
            int row = wr * 64 + i * 16 + l15;
#pragma unroll
            for (int kh = 0; kh < 2; ++kh) {
                int s = kh * 4 + g;
                af[i][kh] = *(const bf16x8*)(&sA[row * 64 + SWZ8(row, s)]);
            }
        }
#pragma unroll
        for (int j = 0; j < NJ; ++j) {
            int row = wc * (BN / 2) + j * 16 + l15;
#pragma unroll
            for (int kh = 0; kh < 2; ++kh) {
                int s = kh * 4 + g;
                bfr[j][kh] = *(const bf16x8*)(&sB[row * 64 + SWZ8(row, s)]);
            }
        }
#pragma unroll
        for (int kh = 0; kh < 2; ++kh)
#pragma unroll
            for (int i = 0; i < 4; ++i)
#pragma unroll
                for (int j = 0; j < NJ; ++j)
                    acc[i][j] = __builtin_amdgcn_mfma_f32_16x16x32_bf16(af[i][kh], bfr[j][kh], acc[i][j], 0, 0, 0);
    }

#pragma unroll
    for (int i = 0; i < 4; ++i)
#pragma unroll
        for (int j = 0; j < NJ; ++j)
#pragma unroll
            for (int r = 0; r < 4; ++r) {
                int row = by * 128 + wr * 64 + i * 16 + g * 4 + r;
                int col = bx * BN + wc * (BN / 2) + j * 16 + l15;
                if constexpr (C_F32)
                    ((float*)Cv)[(size_t)row * DDIM + col] = acc[i][j][r];
                else
                    ((short*)Cv)[(size_t)row * DDIM + col] = f2bf(acc[i][j][r]);
            }
}

// ---------------------------------------------------------------------------
// Flash attention per (b, h, 64-q-rows). 4 waves x 16 q-rows, KV tiles of 64.
// Fixed-offset softmax (m=0, exact by shift-invariance; scores bounded, clamped
// at 60): p=exp(s), lane-local l accumulation, ONE cross-lane reduce at end.
// TRV: V pre-transposed [b][h][e][s] -> staged via global_load_lds like K.
template<bool TRV>
__global__ __launch_bounds__(256) void attn(const short* __restrict__ q,
                                            const short* __restrict__ k,
                                            const short* __restrict__ v,
                                            const int* __restrict__ vlens,
                                            short* __restrict__ att) {
    const int blk = blockIdx.x;            // 1024
    const int qt = blk >> 6;
    const int hb = blk & 63;
    const int bb = hb & 3;                 // batch varies fastest
    const int h  = hb >> 2;

    const int tid = threadIdx.x;
    const int lane = tid & 63, wid = tid >> 6;
    const int g = lane >> 4, l15 = lane & 15;
    const int vlen = vlens[bb];

    __shared__ short sK[2][64 * 64];       // [key][d-slots] swz by key&7
    __shared__ short sV[2][64 * 64];       // [e][key-slots] swz by e&7
    __shared__ short sP[4][16 * 64];       // per-wave [q][key-slots]

    const int srow = qt * 64 + wid * 16 + l15;
    const short* qrow = q + ((size_t)(bb * SS + srow)) * DDIM + h * 64;
    bf16x8 qf[2];
    qf[0] = *(const bf16x8*)(qrow + g * 8);
    qf[1] = *(const bf16x8*)(qrow + 32 + g * 8);

    float lsum[4] = {0.f, 0.f, 0.f, 0.f};
    f32x4 oacc[4] = {};

    const int key0 = tid >> 3, key1 = (tid + 256) >> 3, sp = tid & 7;
    const int d0 = (tid & 7) << 3;
    const short* vTb = v + ((size_t)(bb * HH + h) * 64) * SS;   // TRV base

    const int ntiles = (vlen + 63) >> 6;

    // ---- prologue: stage tile 0 into buf 0 ----
    {
        GL_LDS16(k + ((size_t)(bb * SS + key0)) * DDIM + h * 64 + ((sp ^ (key0 & 7)) << 3),
                 (char*)&sK[0][0] + tid * 16);
        GL_LDS16(k + ((size_t)(bb * SS + key1)) * DDIM + h * 64 + ((sp ^ (key1 & 7)) << 3),
                 (char*)&sK[0][0] + (tid + 256) * 16);
        if constexpr (TRV) {
            GL_LDS16(vTb + (size_t)key0 * SS + ((sp ^ (key0 & 7)) << 3),
                     (char*)&sV[0][0] + tid * 16);
            GL_LDS16(vTb + (size_t)key1 * SS + ((sp ^ (key1 & 7)) << 3),
                     (char*)&sV[0][0] + (tid + 256) * 16);
        } else {
            bf16x8 v0 = *(const bf16x8*)(v + ((size_t)(bb * SS + key0)) * DDIM + h * 64 + d0);
            bf16x8 v1 = *(const bf16x8*)(v + ((size_t)(bb * SS + key1)) * DDIM + h * 64 + d0);
#pragma unroll
            for (int e = 0; e < 8; ++e) {
                int e0 = d0 + e;
                sV[0][e0 * 64 + (((key0 >> 3) ^ (e0 & 7)) << 3) + (key0 & 7)] = v0[e];
                sV[0][e0 * 64 + (((key1 >> 3) ^ (e0 & 7)) << 3) + (key1 & 7)] = v1[e];
            }
        }
    }
    __syncthreads();

    for (int t = 0; t < ntiles; ++t) {
        const int cur = t & 1, nxt = cur ^ 1;
        const int kb = t * 64;
        const bool pre = (t + 1 < ntiles);

        // ---- issue next-tile staging before compute ----
        bf16x8 vr0, vr1;
        if (pre) {
            const int kb2 = kb + 64;
            GL_LDS16(k + ((size_t)(bb * SS + kb2 + key0)) * DDIM + h * 64 + ((sp ^ (key0 & 7)) << 3),
                     (char*)&sK[nxt][0] + tid * 16);
            GL_LDS16(k + ((size_t)(bb * SS + kb2 + key1)) * DDIM + h * 64 + ((sp ^ (key1 & 7)) << 3),
                     (char*)&sK[nxt][0] + (tid + 256) * 16);
            if constexpr (TRV) {
                GL_LDS16(vTb + (size_t)key0 * SS + kb2 + ((sp ^ (key0 & 7)) << 3),
                         (char*)&sV[nxt][0] + tid * 16);
                GL_LDS16(vTb + (size_t)key1 * SS + kb2 + ((sp ^ (key1 & 7)) << 3),
                         (char*)&sV[nxt][0] + (tid + 256) * 16);
            } else {
                vr0 = *(const bf16x8*)(v + ((size_t)(bb * SS + kb2 + key0)) * DDIM + h * 64 + d0);
                vr1 = *(const bf16x8*)(v + ((size_t)(bb * SS + kb2 + key1)) * DDIM + h * 64 + d0);
            }
        }

        // ---- QK^T on buf[cur] ----
        f32x4 sacc[4] = {};
#pragma unroll
        for (int kg = 0; kg < 4; ++kg) {
            int row = kg * 16 + l15;
#pragma unroll
            for (int kh = 0; kh < 2; ++kh) {
                int s = kh * 4 + g;
                bf16x8 kf = *(const bf16x8*)(&sK[cur][row * 64 + ((s ^ (row & 7)) << 3)]);
                sacc[kg] = __builtin_amdgcn_mfma_f32_16x16x32_bf16(qf[kh], kf, sacc[kg], 0, 0, 0);
            }
        }

        // ---- softmax, fixed offset (no cross-lane ops) ----
#pragma unroll
        for (int r = 0; r < 4; ++r) {
            float p[4], ls = 0.f;
#pragma unroll
            for (int kg = 0; kg < 4; ++kg) {
                float s = fminf(sacc[kg][r] * 0.125f, 60.0f);
                if (kb + kg * 16 + l15 >= vlen) s = -1e30f;
                p[kg] = __expf(s);
                ls += p[kg];
            }
            lsum[r] += ls;
            const int srw = g * 4 + r;
#pragma unroll
            for (int kg = 0; kg < 4; ++kg) {
                int col = kg * 16 + l15;
                sP[wid][srw * 64 + (((col >> 3) ^ (srw & 7)) << 3) + (col & 7)] = f2bf(p[kg]);
            }
        }

        // ---- PV on buf[cur] (no rescale) ----
        bf16x8 pf[2];
#pragma unroll
        for (int kh = 0; kh < 2; ++kh) {
            int s = kh * 4 + g;
            pf[kh] = *(const bf16x8*)(&sP[wid][l15 * 64 + ((s ^ (l15 & 7)) << 3)]);
        }
#pragma unroll
        for (int n = 0; n < 4; ++n) {
            const int e = n * 16 + l15;
#pragma unroll
            for (int kh = 0; kh < 2; ++kh) {
                int s = kh * 4 + g;
                bf16x8 vf = *(const bf16x8*)(&sV[cur][e * 64 + ((s ^ (e & 7)) << 3)]);
                oacc[n] = __builtin_amdgcn_mfma_f32_16x16x32_bf16(pf[kh], vf, oacc[n], 0, 0, 0);
            }
        }

        // ---- late write of prefetched V (non-TRV only) ----
        if constexpr (!TRV) {
            if (pre) {
#pragma unroll
                for (int e = 0; e < 8; ++e) {
                    int e0 = d0 + e;
                    sV[nxt][e0 * 64 + (((key0 >> 3) ^ (e0 & 7)) << 3) + (key0 & 7)] = vr0[e];
                    sV[nxt][e0 * 64 + (((key1 >> 3) ^ (e0 & 7)) << 3) + (key1 & 7)] = vr1[e];
                }
            }
        }
        __syncthreads();
    }

    // ---- epilogue: single 16-lane reduction of l per q-row ----
#pragma unroll
    for (int r = 0; r < 4; ++r) {
        float rs = lsum[r];
#pragma unroll
        for (int off = 1; off < 16; off <<= 1)
            rs += __shfl_xor(rs, off);
        lsum[r] = rs;
    }

    // write head-interleaved: att[bb][s][e*H + h]
#pragma unroll
    for (int n = 0; n < 4; ++n)
#pragma unroll
        for (int r = 0; r < 4; ++r) {
            float o = oacc[n][r] / lsum[r];
            int sg = qt * 64 + wid * 16 + g * 4 + r;
            int e = n * 16 + l15;
            att[((size_t)(bb * SS + sg)) * DDIM + e * HH + h] = f2bf(o);
        }
}

extern "C" void kernel_launch(void* const* d_in, const int* in_sizes, int n_in,
                              void* d_out, int out_size, void* d_ws, size_t ws_size,
                              hipStream_t stream) {
    const float* queries = (const float*)d_in[0];
    const float* keys    = (const float*)d_in[1];
    const float* values  = (const float*)d_in[2];
    const int*   vlens   = (const int*)d_in[3];
    const float* Wq      = (const float*)d_in[4];
    const float* Wk      = (const float*)d_in[5];
    const float* Wv      = (const float*)d_in[6];
    const float* Wo      = (const float*)d_in[7];
    float* out = (float*)d_out;

    short* ws = (short*)d_ws;
    const size_t sz = (size_t)MROWS * DDIM;   // 4M elems, 8MB per region
    short* q_ws   = ws;
    short* k_ws   = ws + sz;
    short* v_ws   = ws + 2 * sz;
    short* att_ws = ws + 3 * sz;
    short* wt3  = att_ws;                     // dead until attn writes
    short* wt_o = q_ws;                       // dead after attn reads q

    dim3 tgrid3(16, 16, 3);
    dim3 tgrid1(16, 16, 1);
    dim3 vgrid(16, 16, 4);

    const size_t regionB = sz * sizeof(short);
    const bool big = ws_size >= 7 * regionB;   // cvt buffers + vT
    const bool mid = ws_size >= 5 * regionB;   // vT only

    if (big) {
        short* qb = ws + 4 * sz;
        short* kb = ws + 5 * sz;
        short* vb = ws + 6 * sz;
        cvtA3<<<dim3(2048, 3), 256, 0, stream>>>(queries, keys, values, qb, vlens);
        transposeW3<<<tgrid3, 256, 0, stream>>>(Wq, Wk, Wv, wt3);
        gemm<false, false, 128, true><<<dim3(768), 256, 0, stream>>>(
            qb, kb, vb, wt3, q_ws, k_ws, v_ws, vlens);
        transposeV<<<vgrid, 256, 0, stream>>>(v_ws, qb, vlens);   // qb dead now
        attn<true><<<dim3(1024), 256, 0, stream>>>(q_ws, k_ws, qb, vlens, att_ws);
    } else if (mid) {
        short* vT = ws + 4 * sz;
        transposeW3<<<tgrid3, 256, 0, stream>>>(Wq, Wk, Wv, wt3);
        gemm<true, false, 128, true><<<dim3(768), 256, 0, stream>>>(
            queries, keys, values, wt3, q_ws, k_ws, v_ws, vlens);
        transposeV<<<vgrid, 256, 0, stream>>>(v_ws, vT, vlens);
        attn<true><<<dim3(1024), 256, 0, stream>>>(q_ws, k_ws, vT, vlens, att_ws);
    } else {
        transposeW3<<<tgrid3, 256, 0, stream>>>(Wq, Wk, Wv, wt3);
        gemm<true, false, 128, true><<<dim3(768), 256, 0, stream>>>(
            queries, keys, values, wt3, q_ws, k_ws, v_ws, vlens);
        attn<false><<<dim3(1024), 256, 0, stream>>>(q_ws, k_ws, v_ws, vlens, att_ws);
    }

    transposeW3<<<tgrid1, 256, 0, stream>>>(Wo, Wo, Wo, wt_o);
    gemm<false, true, 64, false><<<dim3(512), 256, 0, stream>>>(
        att_ws, att_ws, att_ws, wt_o, out, out, out, vlens);
}

// Round 13
// 94.663 us; speedup vs baseline: 1.5778x; 1.0438x over previous
//
#include <hip/hip_runtime.h>
#include <hip/hip_bf16.h>

#define BB 4
#define SS 1024
#define DDIM 1024
#define HH 16
#define MROWS (BB * SS)

typedef __attribute__((ext_vector_type(8))) short bf16x8;
typedef __attribute__((ext_vector_type(4))) float f32x4;

static __device__ __forceinline__ short f2bf(float x) {
    union { __hip_bfloat16 h; short s; } u;
    u.h = __float2bfloat16(x);
    return u.s;
}

#define GL_LDS16(gp, lp)                                                      \
    __builtin_amdgcn_global_load_lds(                                         \
        (const __attribute__((address_space(1))) void*)(gp),                  \
        (__attribute__((address_space(3))) void*)(lp), 16, 0, 0)

// 128B-row swizzle (8 x 16B slots): physical slot = s ^ (row&7).
#define SWZ8(row, s) (((s) ^ ((row) & 7)) << 3)

// ---------------------------------------------------------------------------
// Shared transpose helper body: W [K,N] f32 64x64 tile -> dst [N,K] bf16.
static __device__ __forceinline__ void transposeW_body(const float* __restrict__ W,
                                                       short* __restrict__ dst,
                                                       int k0, int n0,
                                                       short (*sT)[72], int t) {
    {
        int r = t >> 2, cq = (t & 3) << 4;
        const float* p = W + (size_t)(k0 + r) * DDIM + n0 + cq;
        float4 a = ((const float4*)p)[0], b = ((const float4*)p)[1];
        float4 c = ((const float4*)p)[2], d = ((const float4*)p)[3];
        short* dp = &sT[r][cq];
        dp[0]  = f2bf(a.x); dp[1]  = f2bf(a.y); dp[2]  = f2bf(a.z); dp[3]  = f2bf(a.w);
        dp[4]  = f2bf(b.x); dp[5]  = f2bf(b.y); dp[6]  = f2bf(b.z); dp[7]  = f2bf(b.w);
        dp[8]  = f2bf(c.x); dp[9]  = f2bf(c.y); dp[10] = f2bf(c.z); dp[11] = f2bf(c.w);
        dp[12] = f2bf(d.x); dp[13] = f2bf(d.y); dp[14] = f2bf(d.z); dp[15] = f2bf(d.w);
    }
    __syncthreads();
    {
        int n = t >> 2, kq = (t & 3) << 4;
        bf16x8 o0, o1;
#pragma unroll
        for (int j = 0; j < 8; ++j) o0[j] = sT[kq + j][n];
#pragma unroll
        for (int j = 0; j < 8; ++j) o1[j] = sT[kq + 8 + j][n];
        short* q = dst + (size_t)(n0 + n) * DDIM + k0 + kq;
        *(bf16x8*)q = o0;
        *(bf16x8*)(q + 8) = o1;
    }
}

// ---------------------------------------------------------------------------
// PREP (merged): blocks [0,6144): f32->bf16 cvt of Q/K/V activations (z=blk/2048,
// vlen-skipped for K/V). Blocks [6144,6912): transposeW of Wq/Wk/Wv -> wt3.
__global__ __launch_bounds__(256) void prep(const float* __restrict__ X0,
                                            const float* __restrict__ X1,
                                            const float* __restrict__ X2,
                                            const float* __restrict__ W0,
                                            const float* __restrict__ W1,
                                            const float* __restrict__ W2,
                                            short* __restrict__ dstA,
                                            short* __restrict__ Wt,
                                            const int* __restrict__ vlens) {
    __shared__ short sT[64][72];
    const int bx = blockIdx.x;
    const int t = threadIdx.x;
    if (bx >= 6144) {
        const int w = bx - 6144;            // 0..767
        const int z = w >> 8;
        const int rem = w & 255;
        const float* W = (z == 0) ? W0 : (z == 1) ? W1 : W2;
        transposeW_body(W, Wt + (size_t)z * DDIM * DDIM,
                        (rem >> 4) * 64, (rem & 15) * 64, sT, t);
        return;
    }
    const int z = bx >> 11;
    const int blk = bx & 2047;              // 2 rows each
    const int row0 = blk << 1;
    if (z >= 1) {
        const int bb = row0 >> 10;
        if ((row0 & 1023) >= vlens[bb]) return;
    }
    const float* X = (z == 0) ? X0 : (z == 1) ? X1 : X2;
    short* D = dstA + (size_t)z * MROWS * DDIM;
    const size_t base = (size_t)blk * 2048 + t * 8;
    const float4 x0 = ((const float4*)(X + base))[0];
    const float4 x1 = ((const float4*)(X + base))[1];
    bf16x8 vv;
    vv[0] = f2bf(x0.x); vv[1] = f2bf(x0.y); vv[2] = f2bf(x0.z); vv[3] = f2bf(x0.w);
    vv[4] = f2bf(x1.x); vv[5] = f2bf(x1.y); vv[6] = f2bf(x1.z); vv[7] = f2bf(x1.w);
    *(bf16x8*)(D + base) = vv;
}

// ---------------------------------------------------------------------------
// POST (merged, runs after QKV gemm, before attn):
// z<4: V [b][s][h*64+e] -> vT [b][h][e][s] (vlen-skipped).  z==4: Wo -> wt_o.
__global__ __launch_bounds__(256) void post(const short* __restrict__ v,
                                            short* __restrict__ vT,
                                            const float* __restrict__ Wo,
                                            short* __restrict__ wt_o,
                                            const int* __restrict__ vlens) {
    __shared__ short sT[64][72];
    const int t = threadIdx.x;
    const int z = blockIdx.z;
    if (z == 4) {
        transposeW_body(Wo, wt_o, blockIdx.y * 64, blockIdx.x * 64, sT, t);
        return;
    }
    const int st = blockIdx.x, h = blockIdx.y, bb = z;
    if (st * 64 >= vlens[bb]) return;
#pragma unroll
    for (int j = 0; j < 2; ++j) {
        int c = t + j * 256;
        int sr = c >> 3, co = (c & 7) << 3;
        *(bf16x8*)(&sT[sr][co]) =
            *(const bf16x8*)(v + (size_t)(bb * SS + st * 64 + sr) * DDIM + h * 64 + co);
    }
    __syncthreads();
    {
        int e = t >> 2, sq = (t & 3) << 4;
        bf16x8 o0, o1;
#pragma unroll
        for (int j = 0; j < 8; ++j) o0[j] = sT[sq + j][e];
#pragma unroll
        for (int j = 0; j < 8; ++j) o1[j] = sT[sq + 8 + j][e];
        short* dst = vT + ((size_t)(bb * HH + h) * 64 + e) * SS + st * 64 + sq;
        *(bf16x8*)dst = o0;
        *(bf16x8*)(dst + 8) = o1;
    }
}

// ---------------------------------------------------------------------------
// Fallback standalone kernels (mid/small-ws paths).
__global__ __launch_bounds__(256) void transposeW3(const float* __restrict__ W0,
                                                   const float* __restrict__ W1,
                                                   const float* __restrict__ W2,
                                                   short* __restrict__ Wt) {
    __shared__ short sT[64][72];
    const int z = blockIdx.z;
    const float* W = (z == 0) ? W0 : (z == 1) ? W1 : W2;
    transposeW_body(W, Wt + (size_t)z * DDIM * DDIM,
                    blockIdx.y * 64, blockIdx.x * 64, sT, threadIdx.x);
}

__global__ __launch_bounds__(256) void transposeV(const short* __restrict__ v,
                                                  short* __restrict__ vT,
                                                  const int* __restrict__ vlens) {
    const int st = blockIdx.x, h = blockIdx.y, bb = blockIdx.z;
    if (st * 64 >= vlens[bb]) return;
    __shared__ short sT[64][72];
    const int t = threadIdx.x;
#pragma unroll
    for (int j = 0; j < 2; ++j) {
        int c = t + j * 256;
        int sr = c >> 3, co = (c & 7) << 3;
        *(bf16x8*)(&sT[sr][co]) =
            *(const bf16x8*)(v + (size_t)(bb * SS + st * 64 + sr) * DDIM + h * 64 + co);
    }
    __syncthreads();
    {
        int e = t >> 2, sq = (t & 3) << 4;
        bf16x8 o0, o1;
#pragma unroll
        for (int j = 0; j < 8; ++j) o0[j] = sT[sq + j][e];
#pragma unroll
        for (int j = 0; j < 8; ++j) o1[j] = sT[sq + 8 + j][e];
        short* dst = vT + ((size_t)(bb * HH + h) * 64 + e) * SS + st * 64 + sq;
        *(bf16x8*)dst = o0;
        *(bf16x8*)(dst + 8) = o1;
    }
}

// ---------------------------------------------------------------------------
// C[z][M,N] = A[z][M,K] @ Bt[z][N,K]^T, up to 3 fused problems.
// m97 structure: BM=128, BN template, BK=64, SINGLE LDS buffer, 2 barriers
// per K-step, 32 MFMA/wave/step, pure global_load_lds staging (bf16 path),
// swizzle (s ^ (row&7))<<3 on both sides. XCD-chunked grid; vlen SKIP.
template<bool A_F32, bool C_F32, int BN, bool SKIP>
__global__ __launch_bounds__(256) void gemm(const void* __restrict__ A0v,
                                            const void* __restrict__ A1v,
                                            const void* __restrict__ A2v,
                                            const short* __restrict__ BtBase,
                                            void* __restrict__ C0v,
                                            void* __restrict__ C1v,
                                            void* __restrict__ C2v,
                                            const int* __restrict__ vlens) {
    constexpr int NJ  = BN / 32;
    constexpr int NBX = DDIM / BN;
    constexpr int NPB = 32 * NBX;
    constexpr int BCH = BN / 32;

    __shared__ short sA[128 * 64];
    __shared__ short sB[BN * 64];

    const int tid = threadIdx.x;
    const int lane = tid & 63, wid = tid >> 6;
    const int wr = wid >> 1, wc = wid & 1;
    const int g = lane >> 4, l15 = lane & 15;

    const int blk = blockIdx.x;
    const int z = blk / NPB;
    const int inner = blk % NPB;
    const int xcd = inner & 7, ii = inner >> 3;
    const int by = xcd * 4 + ii / NBX;
    const int bx = ii % NBX;

    if constexpr (SKIP) {
        if (z >= 1 && ((by & 7) << 7) >= vlens[by >> 3]) return;
    }

    const void* Av = (z == 0) ? A0v : (z == 1) ? A1v : A2v;
    const short* Bt = BtBase + (size_t)z * DDIM * DDIM;
    void* Cv = (z == 0) ? C0v : (z == 1) ? C1v : C2v;
    const float* Af = (const float*)Av;
    const short* Ab = (const short*)Av;
    const int K = DDIM;

    f32x4 acc[4][NJ] = {};
    const int nkt = K >> 6;

    for (int t = 0; t < nkt; ++t) {
        const int kt = t << 6;
        __syncthreads();

        if constexpr (A_F32) {
            float4 ra[4][2];
#pragma unroll
            for (int j = 0; j < 4; ++j) {
                int c = tid + j * 256;
                int row = c >> 3, s = c & 7;
                const float* p = Af + (size_t)(by * 128 + row) * K + kt + s * 8;
                ra[j][0] = ((const float4*)p)[0];
                ra[j][1] = ((const float4*)p)[1];
            }
#pragma unroll
            for (int j = 0; j < 4; ++j) {
                int c = tid + j * 256;
                int row = c >> 3, s = c & 7;
                bf16x8 vv;
                vv[0] = f2bf(ra[j][0].x); vv[1] = f2bf(ra[j][0].y);
                vv[2] = f2bf(ra[j][0].z); vv[3] = f2bf(ra[j][0].w);
                vv[4] = f2bf(ra[j][1].x); vv[5] = f2bf(ra[j][1].y);
                vv[6] = f2bf(ra[j][1].z); vv[7] = f2bf(ra[j][1].w);
                *(bf16x8*)(&sA[row * 64 + SWZ8(row, s)]) = vv;
            }
        } else {
#pragma unroll
            for (int j = 0; j < 4; ++j) {
                int c = tid + j * 256;
                int row = c >> 3, sp = c & 7;
                GL_LDS16(Ab + (size_t)(by * 128 + row) * K + kt + SWZ8(row, sp),
                         (char*)&sA[0] + c * 16);
            }
        }
#pragma unroll
        for (int j = 0; j < BCH; ++j) {
            int c = tid + j * 256;
            int row = c >> 3, sp = c & 7;
            GL_LDS16(Bt + (size_t)(bx * BN + row) * K + kt + SWZ8(row, sp),
                     (char*)&sB[0] + c * 16);
        }
        __syncthreads();

        bf16x8 af[4][2], bfr[NJ][2];
#pragma unroll
        for (int i = 0; i < 4; ++i) {
            int row = wr * 64 + i * 16 + l15;
#pragma unroll
            for (int kh = 0; kh < 2; ++kh) {
                int s = kh * 4 + g;
                af[i][kh] = *(const bf16x8*)(&sA[row * 64 + SWZ8(row, s)]);
            }
        }
#pragma unroll
        for (int j = 0; j < NJ; ++j) {
            int row = wc * (BN / 2) + j * 16 + l15;
#pragma unroll
            for (int kh = 0; kh < 2; ++kh) {
                int s = kh * 4 + g;
                bfr[j][kh] = *(const bf16x8*)(&sB[row * 64 + SWZ8(row, s)]);
            }
        }
#pragma unroll
        for (int kh = 0; kh < 2; ++kh)
#pragma unroll
            for (int i = 0; i < 4; ++i)
#pragma unroll
                for (int j = 0; j < NJ; ++j)
                    acc[i][j] = __builtin_amdgcn_mfma_f32_16x16x32_bf16(af[i][kh], bfr[j][kh], acc[i][j], 0, 0, 0);
    }

#pragma unroll
    for (int i = 0; i < 4; ++i)
#pragma unroll
        for (int j = 0; j < NJ; ++j)
#pragma unroll
            for (int r = 0; r < 4; ++r) {
                int row = by * 128 + wr * 64 + i * 16 + g * 4 + r;
                int col = bx * BN + wc * (BN / 2) + j * 16 + l15;
                if constexpr (C_F32)
                    ((float*)Cv)[(size_t)row * DDIM + col] = acc[i][j][r];
                else
                    ((short*)Cv)[(size_t)row * DDIM + col] = f2bf(acc[i][j][r]);
            }
}

// ---------------------------------------------------------------------------
// Flash attention per (b, h, 64-q-rows). 4 waves x 16 q-rows, KV tiles of 64.
// Fixed-offset softmax (m=0, exact by shift-invariance; scores bounded, clamped
// at 60): p=exp(s), lane-local l accumulation, ONE cross-lane reduce at end.
// TRV: V pre-transposed [b][h][e][s] -> staged via global_load_lds like K.
template<bool TRV>
__global__ __launch_bounds__(256) void attn(const short* __restrict__ q,
                                            const short* __restrict__ k,
                                            const short* __restrict__ v,
                                            const int* __restrict__ vlens,
                                            short* __restrict__ att) {
    const int blk = blockIdx.x;            // 1024
    const int qt = blk >> 6;
    const int hb = blk & 63;
    const int bb = hb & 3;                 // batch varies fastest
    const int h  = hb >> 2;

    const int tid = threadIdx.x;
    const int lane = tid & 63, wid = tid >> 6;
    const int g = lane >> 4, l15 = lane & 15;
    const int vlen = vlens[bb];

    __shared__ short sK[2][64 * 64];
    __shared__ short sV[2][64 * 64];
    __shared__ short sP[4][16 * 64];

    const int srow = qt * 64 + wid * 16 + l15;
    const short* qrow = q + ((size_t)(bb * SS + srow)) * DDIM + h * 64;
    bf16x8 qf[2];
    qf[0] = *(const bf16x8*)(qrow + g * 8);
    qf[1] = *(const bf16x8*)(qrow + 32 + g * 8);

    float lsum[4] = {0.f, 0.f, 0.f, 0.f};
    f32x4 oacc[4] = {};

    const int key0 = tid >> 3, key1 = (tid + 256) >> 3, sp = tid & 7;
    const int d0 = (tid & 7) << 3;
    const short* vTb = v + ((size_t)(bb * HH + h) * 64) * SS;

    const int ntiles = (vlen + 63) >> 6;

    {
        GL_LDS16(k + ((size_t)(bb * SS + key0)) * DDIM + h * 64 + ((sp ^ (key0 & 7)) << 3),
                 (char*)&sK[0][0] + tid * 16);
        GL_LDS16(k + ((size_t)(bb * SS + key1)) * DDIM + h * 64 + ((sp ^ (key1 & 7)) << 3),
                 (char*)&sK[0][0] + (tid + 256) * 16);
        if constexpr (TRV) {
            GL_LDS16(vTb + (size_t)key0 * SS + ((sp ^ (key0 & 7)) << 3),
                     (char*)&sV[0][0] + tid * 16);
            GL_LDS16(vTb + (size_t)key1 * SS + ((sp ^ (key1 & 7)) << 3),
                     (char*)&sV[0][0] + (tid + 256) * 16);
        } else {
            bf16x8 v0 = *(const bf16x8*)(v + ((size_t)(bb * SS + key0)) * DDIM + h * 64 + d0);
            bf16x8 v1 = *(const bf16x8*)(v + ((size_t)(bb * SS + key1)) * DDIM + h * 64 + d0);
#pragma unroll
            for (int e = 0; e < 8; ++e) {
                int e0 = d0 + e;
                sV[0][e0 * 64 + (((key0 >> 3) ^ (e0 & 7)) << 3) + (key0 & 7)] = v0[e];
                sV[0][e0 * 64 + (((key1 >> 3) ^ (e0 & 7)) << 3) + (key1 & 7)] = v1[e];
            }
        }
    }
    __syncthreads();

    for (int t = 0; t < ntiles; ++t) {
        const int cur = t & 1, nxt = cur ^ 1;
        const int kb = t * 64;
        const bool pre = (t + 1 < ntiles);

        bf16x8 vr0, vr1;
        if (pre) {
            const int kb2 = kb + 64;
            GL_LDS16(k + ((size_t)(bb * SS + kb2 + key0)) * DDIM + h * 64 + ((sp ^ (key0 & 7)) << 3),
                     (char*)&sK[nxt][0] + tid * 16);
            GL_LDS16(k + ((size_t)(bb * SS + kb2 + key1)) * DDIM + h * 64 + ((sp ^ (key1 & 7)) << 3),
                     (char*)&sK[nxt][0] + (tid + 256) * 16);
            if constexpr (TRV) {
                GL_LDS16(vTb + (size_t)key0 * SS + kb2 + ((sp ^ (key0 & 7)) << 3),
                         (char*)&sV[nxt][0] + tid * 16);
                GL_LDS16(vTb + (size_t)key1 * SS + kb2 + ((sp ^ (key1 & 7)) << 3),
                         (char*)&sV[nxt][0] + (tid + 256) * 16);
            } else {
                vr0 = *(const bf16x8*)(v + ((size_t)(bb * SS + kb2 + key0)) * DDIM + h * 64 + d0);
                vr1 = *(const bf16x8*)(v + ((size_t)(bb * SS + kb2 + key1)) * DDIM + h * 64 + d0);
            }
        }

        f32x4 sacc[4] = {};
#pragma unroll
        for (int kg = 0; kg < 4; ++kg) {
            int row = kg * 16 + l15;
#pragma unroll
            for (int kh = 0; kh < 2; ++kh) {
                int s = kh * 4 + g;
                bf16x8 kf = *(const bf16x8*)(&sK[cur][row * 64 + ((s ^ (row & 7)) << 3)]);
                sacc[kg] = __builtin_amdgcn_mfma_f32_16x16x32_bf16(qf[kh], kf, sacc[kg], 0, 0, 0);
            }
        }

#pragma unroll
        for (int r = 0; r < 4; ++r) {
            float p[4], ls = 0.f;
#pragma unroll
            for (int kg = 0; kg < 4; ++kg) {
                float s = fminf(sacc[kg][r] * 0.125f, 60.0f);
                if (kb + kg * 16 + l15 >= vlen) s = -1e30f;
                p[kg] = __expf(s);
                ls += p[kg];
            }
            lsum[r] += ls;
            const int srw = g * 4 + r;
#pragma unroll
            for (int kg = 0; kg < 4; ++kg) {
                int col = kg * 16 + l15;
                sP[wid][srw * 64 + (((col >> 3) ^ (srw & 7)) << 3) + (col & 7)] = f2bf(p[kg]);
            }
        }

        bf16x8 pf[2];
#pragma unroll
        for (int kh = 0; kh < 2; ++kh) {
            int s = kh * 4 + g;
            pf[kh] = *(const bf16x8*)(&sP[wid][l15 * 64 + ((s ^ (l15 & 7)) << 3)]);
        }
#pragma unroll
        for (int n = 0; n < 4; ++n) {
            const int e = n * 16 + l15;
#pragma unroll
            for (int kh = 0; kh < 2; ++kh) {
                int s = kh * 4 + g;
                bf16x8 vf = *(const bf16x8*)(&sV[cur][e * 64 + ((s ^ (e & 7)) << 3)]);
                oacc[n] = __builtin_amdgcn_mfma_f32_16x16x32_bf16(pf[kh], vf, oacc[n], 0, 0, 0);
            }
        }

        if constexpr (!TRV) {
            if (pre) {
#pragma unroll
                for (int e = 0; e < 8; ++e) {
                    int e0 = d0 + e;
                    sV[nxt][e0 * 64 + (((key0 >> 3) ^ (e0 & 7)) << 3) + (key0 & 7)] = vr0[e];
                    sV[nxt][e0 * 64 + (((key1 >> 3) ^ (e0 & 7)) << 3) + (key1 & 7)] = vr1[e];
                }
            }
        }
        __syncthreads();
    }

#pragma unroll
    for (int r = 0; r < 4; ++r) {
        float rs = lsum[r];
#pragma unroll
        for (int off = 1; off < 16; off <<= 1)
            rs += __shfl_xor(rs, off);
        lsum[r] = rs;
    }

#pragma unroll
    for (int n = 0; n < 4; ++n)
#pragma unroll
        for (int r = 0; r < 4; ++r) {
            float o = oacc[n][r] / lsum[r];
            int sg = qt * 64 + wid * 16 + g * 4 + r;
            int e = n * 16 + l15;
            att[((size_t)(bb * SS + sg)) * DDIM + e * HH + h] = f2bf(o);
        }
}

extern "C" void kernel_launch(void* const* d_in, const int* in_sizes, int n_in,
                              void* d_out, int out_size, void* d_ws, size_t ws_size,
                              hipStream_t stream) {
    const float* queries = (const float*)d_in[0];
    const float* keys    = (const float*)d_in[1];
    const float* values  = (const float*)d_in[2];
    const int*   vlens   = (const int*)d_in[3];
    const float* Wq      = (const float*)d_in[4];
    const float* Wk      = (const float*)d_in[5];
    const float* Wv      = (const float*)d_in[6];
    const float* Wo      = (const float*)d_in[7];
    float* out = (float*)d_out;

    short* ws = (short*)d_ws;
    const size_t sz = (size_t)MROWS * DDIM;   // 4M elems, 8MB per region
    short* q_ws   = ws;
    short* k_ws   = ws + sz;
    short* v_ws   = ws + 2 * sz;
    short* att_ws = ws + 3 * sz;
    short* wt3  = att_ws;                     // dead until attn writes

    const size_t regionB = sz * sizeof(short);
    const bool big = ws_size >= 7 * regionB;
    const bool mid = ws_size >= 5 * regionB;

    if (big) {
        short* qb = ws + 4 * sz;              // cvt Q; later vT
        short* kb = ws + 5 * sz;              // cvt K
        short* vb = ws + 6 * sz;              // cvt V; later wt_o
        // prep: cvt QKV (6144 blocks) + transpose Wq/Wk/Wv (768 blocks)
        prep<<<dim3(6912), 256, 0, stream>>>(queries, keys, values,
                                             Wq, Wk, Wv, qb, wt3, vlens);
        gemm<false, false, 128, true><<<dim3(768), 256, 0, stream>>>(
            qb, kb, vb, wt3, q_ws, k_ws, v_ws, vlens);
        // post: transposeV (v_ws -> qb) + transpose Wo (-> vb)
        post<<<dim3(16, 16, 5), 256, 0, stream>>>(v_ws, qb, Wo, vb, vlens);
        attn<true><<<dim3(1024), 256, 0, stream>>>(q_ws, k_ws, qb, vlens, att_ws);
        gemm<false, true, 64, false><<<dim3(512), 256, 0, stream>>>(
            att_ws, att_ws, att_ws, vb, out, out, out, vlens);
    } else if (mid) {
        short* vT = ws + 4 * sz;
        short* wt_o = q_ws;                   // dead after attn reads q
        transposeW3<<<dim3(16, 16, 3), 256, 0, stream>>>(Wq, Wk, Wv, wt3);
        gemm<true, false, 128, true><<<dim3(768), 256, 0, stream>>>(
            queries, keys, values, wt3, q_ws, k_ws, v_ws, vlens);
        transposeV<<<dim3(16, 16, 4), 256, 0, stream>>>(v_ws, vT, vlens);
        attn<true><<<dim3(1024), 256, 0, stream>>>(q_ws, k_ws, vT, vlens, att_ws);
        transposeW3<<<dim3(16, 16, 1), 256, 0, stream>>>(Wo, Wo, Wo, wt_o);
        gemm<false, true, 64, false><<<dim3(512), 256, 0, stream>>>(
            att_ws, att_ws, att_ws, wt_o, out, out, out, vlens);
    } else {
        short* wt_o = q_ws;
        transposeW3<<<dim3(16, 16, 3), 256, 0, stream>>>(Wq, Wk, Wv, wt3);
        gemm<true, false, 128, true><<<dim3(768), 256, 0, stream>>>(
            queries, keys, values, wt3, q_ws, k_ws, v_ws, vlens);
        attn<false><<<dim3(1024), 256, 0, stream>>>(q_ws, k_ws, v_ws, vlens, att_ws);
        transposeW3<<<dim3(16, 16, 1), 256, 0, stream>>>(Wo, Wo, Wo, wt_o);
        gemm<false, true, 64, false><<<dim3(512), 256, 0, stream>>>(
            att_ws, att_ws, att_ws, wt_o, out, out, out, vlens);
    }
}

// Round 15
// 90.900 us; speedup vs baseline: 1.6431x; 1.0414x over previous
//
#include <hip/hip_runtime.h>
#include <hip/hip_bf16.h>

#define BB 4
#define SS 1024
#define DDIM 1024
#define HH 16
#define MROWS (BB * SS)

typedef __attribute__((ext_vector_type(8))) short bf16x8;
typedef __attribute__((ext_vector_type(4))) float f32x4;

static __device__ __forceinline__ short f2bf(float x) {
    union { __hip_bfloat16 h; short s; } u;
    u.h = __float2bfloat16(x);
    return u.s;
}

#define GL_LDS16(gp, lp)                                                      \
    __builtin_amdgcn_global_load_lds(                                         \
        (const __attribute__((address_space(1))) void*)(gp),                  \
        (__attribute__((address_space(3))) void*)(lp), 16, 0, 0)

// 128B-row swizzle (8 x 16B slots): physical slot = s ^ (row&7).
#define SWZ8(row, s) (((s) ^ ((row) & 7)) << 3)

// ---------------------------------------------------------------------------
// Shared transpose helper body: W [K,N] f32 64x64 tile -> dst [N,K] bf16.
static __device__ __forceinline__ void transposeW_body(const float* __restrict__ W,
                                                       short* __restrict__ dst,
                                                       int k0, int n0,
                                                       short (*sT)[72], int t) {
    {
        int r = t >> 2, cq = (t & 3) << 4;
        const float* p = W + (size_t)(k0 + r) * DDIM + n0 + cq;
        float4 a = ((const float4*)p)[0], b = ((const float4*)p)[1];
        float4 c = ((const float4*)p)[2], d = ((const float4*)p)[3];
        short* dp = &sT[r][cq];
        dp[0]  = f2bf(a.x); dp[1]  = f2bf(a.y); dp[2]  = f2bf(a.z); dp[3]  = f2bf(a.w);
        dp[4]  = f2bf(b.x); dp[5]  = f2bf(b.y); dp[6]  = f2bf(b.z); dp[7]  = f2bf(b.w);
        dp[8]  = f2bf(c.x); dp[9]  = f2bf(c.y); dp[10] = f2bf(c.z); dp[11] = f2bf(c.w);
        dp[12] = f2bf(d.x); dp[13] = f2bf(d.y); dp[14] = f2bf(d.z); dp[15] = f2bf(d.w);
    }
    __syncthreads();
    {
        int n = t >> 2, kq = (t & 3) << 4;
        bf16x8 o0, o1;
#pragma unroll
        for (int j = 0; j < 8; ++j) o0[j] = sT[kq + j][n];
#pragma unroll
        for (int j = 0; j < 8; ++j) o1[j] = sT[kq + 8 + j][n];
        short* q = dst + (size_t)(n0 + n) * DDIM + k0 + kq;
        *(bf16x8*)q = o0;
        *(bf16x8*)(q + 8) = o1;
    }
}

// ---------------------------------------------------------------------------
// PREP (merged): blocks [0,6144): f32->bf16 cvt of Q/K/V activations
// (vlen-skipped for K/V). Blocks [6144,6912): transposeW of Wq/Wk/Wv.
__global__ __launch_bounds__(256) void prep(const float* __restrict__ X0,
                                            const float* __restrict__ X1,
                                            const float* __restrict__ X2,
                                            const float* __restrict__ W0,
                                            const float* __restrict__ W1,
                                            const float* __restrict__ W2,
                                            short* __restrict__ dstA,
                                            short* __restrict__ Wt,
                                            const int* __restrict__ vlens) {
    __shared__ short sT[64][72];
    const int bx = blockIdx.x;
    const int t = threadIdx.x;
    if (bx >= 6144) {
        const int w = bx - 6144;
        const int z = w >> 8;
        const int rem = w & 255;
        const float* W = (z == 0) ? W0 : (z == 1) ? W1 : W2;
        transposeW_body(W, Wt + (size_t)z * DDIM * DDIM,
                        (rem >> 4) * 64, (rem & 15) * 64, sT, t);
        return;
    }
    const int z = bx >> 11;
    const int blk = bx & 2047;
    const int row0 = blk << 1;
    if (z >= 1) {
        const int bb = row0 >> 10;
        if ((row0 & 1023) >= vlens[bb]) return;
    }
    const float* X = (z == 0) ? X0 : (z == 1) ? X1 : X2;
    short* D = dstA + (size_t)z * MROWS * DDIM;
    const size_t base = (size_t)blk * 2048 + t * 8;
    const float4 x0 = ((const float4*)(X + base))[0];
    const float4 x1 = ((const float4*)(X + base))[1];
    bf16x8 vv;
    vv[0] = f2bf(x0.x); vv[1] = f2bf(x0.y); vv[2] = f2bf(x0.z); vv[3] = f2bf(x0.w);
    vv[4] = f2bf(x1.x); vv[5] = f2bf(x1.y); vv[6] = f2bf(x1.z); vv[7] = f2bf(x1.w);
    *(bf16x8*)(D + base) = vv;
}

// ---------------------------------------------------------------------------
// Fallback standalone kernels (mid/small-ws paths).
__global__ __launch_bounds__(256) void transposeW3(const float* __restrict__ W0,
                                                   const float* __restrict__ W1,
                                                   const float* __restrict__ W2,
                                                   short* __restrict__ Wt) {
    __shared__ short sT[64][72];
    const int z = blockIdx.z;
    const float* W = (z == 0) ? W0 : (z == 1) ? W1 : W2;
    transposeW_body(W, Wt + (size_t)z * DDIM * DDIM,
                    blockIdx.y * 64, blockIdx.x * 64, sT, threadIdx.x);
}

__global__ __launch_bounds__(256) void transposeV(const short* __restrict__ v,
                                                  short* __restrict__ vT,
                                                  const int* __restrict__ vlens) {
    const int st = blockIdx.x, h = blockIdx.y, bb = blockIdx.z;
    if (st * 64 >= vlens[bb]) return;
    __shared__ short sT[64][72];
    const int t = threadIdx.x;
#pragma unroll
    for (int j = 0; j < 2; ++j) {
        int c = t + j * 256;
        int sr = c >> 3, co = (c & 7) << 3;
        *(bf16x8*)(&sT[sr][co]) =
            *(const bf16x8*)(v + (size_t)(bb * SS + st * 64 + sr) * DDIM + h * 64 + co);
    }
    __syncthreads();
    {
        int e = t >> 2, sq = (t & 3) << 4;
        bf16x8 o0, o1;
#pragma unroll
        for (int j = 0; j < 8; ++j) o0[j] = sT[sq + j][e];
#pragma unroll
        for (int j = 0; j < 8; ++j) o1[j] = sT[sq + 8 + j][e];
        short* dst = vT + ((size_t)(bb * HH + h) * 64 + e) * SS + st * 64 + sq;
        *(bf16x8*)dst = o0;
        *(bf16x8*)(dst + 8) = o1;
    }
}

// ---------------------------------------------------------------------------
// C[z][M,N] = A[z][M,K] @ Bt[z][N,K]^T, up to 3 fused problems.
// m97 structure: BM=128, BN template, BK=64, single LDS buffer, 2 barriers
// per K-step, 32 MFMA/wave/step, global_load_lds staging, SWZ8 both sides.
// TRC (BN=128 only): z==2 writes C TRANSPOSED to vT[b][h][e][s] via an LDS
// re-stage of the 128x128 tile (sA+sB reused as 32KB scratch).
template<bool A_F32, bool C_F32, int BN, bool SKIP, bool TRC>
__global__ __launch_bounds__(256) void gemm(const void* __restrict__ A0v,
                                            const void* __restrict__ A1v,
                                            const void* __restrict__ A2v,
                                            const short* __restrict__ BtBase,
                                            void* __restrict__ C0v,
                                            void* __restrict__ C1v,
                                            void* __restrict__ C2v,
                                            const int* __restrict__ vlens) {
    constexpr int NJ  = BN / 32;
    constexpr int NBX = DDIM / BN;
    constexpr int NPB = 32 * NBX;
    constexpr int BCH = BN / 32;

    __shared__ short smem[128 * 64 + BN * 64];
    short* sA = smem;
    short* sB = smem + 128 * 64;

    const int tid = threadIdx.x;
    const int lane = tid & 63, wid = tid >> 6;
    const int wr = wid >> 1, wc = wid & 1;
    const int g = lane >> 4, l15 = lane & 15;

    const int blk = blockIdx.x;
    const int z = blk / NPB;
    const int inner = blk % NPB;
    const int xcd = inner & 7, ii = inner >> 3;
    const int by = xcd * 4 + ii / NBX;
    const int bx = ii % NBX;

    if constexpr (SKIP) {
        if (z >= 1 && ((by & 7) << 7) >= vlens[by >> 3]) return;
    }

    const void* Av = (z == 0) ? A0v : (z == 1) ? A1v : A2v;
    const short* Bt = BtBase + (size_t)z * DDIM * DDIM;
    void* Cv = (z == 0) ? C0v : (z == 1) ? C1v : C2v;
    const float* Af = (const float*)Av;
    const short* Ab = (const short*)Av;
    const int K = DDIM;

    f32x4 acc[4][NJ] = {};
    const int nkt = K >> 6;

    for (int t = 0; t < nkt; ++t) {
        const int kt = t << 6;
        __syncthreads();

        if constexpr (A_F32) {
            float4 ra[4][2];
#pragma unroll
            for (int j = 0; j < 4; ++j) {
                int c = tid + j * 256;
                int row = c >> 3, s = c & 7;
                const float* p = Af + (size_t)(by * 128 + row) * K + kt + s * 8;
                ra[j][0] = ((const float4*)p)[0];
                ra[j][1] = ((const float4*)p)[1];
            }
#pragma unroll
            for (int j = 0; j < 4; ++j) {
                int c = tid + j * 256;
                int row = c >> 3, s = c & 7;
                bf16x8 vv;
                vv[0] = f2bf(ra[j][0].x); vv[1] = f2bf(ra[j][0].y);
                vv[2] = f2bf(ra[j][0].z); vv[3] = f2bf(ra[j][0].w);
                vv[4] = f2bf(ra[j][1].x); vv[5] = f2bf(ra[j][1].y);
                vv[6] = f2bf(ra[j][1].z); vv[7] = f2bf(ra[j][1].w);
                *(bf16x8*)(&sA[row * 64 + SWZ8(row, s)]) = vv;
            }
        } else {
#pragma unroll
            for (int j = 0; j < 4; ++j) {
                int c = tid + j * 256;
                int row = c >> 3, sp = c & 7;
                GL_LDS16(Ab + (size_t)(by * 128 + row) * K + kt + SWZ8(row, sp),
                         (char*)sA + c * 16);
            }
        }
#pragma unroll
        for (int j = 0; j < BCH; ++j) {
            int c = tid + j * 256;
            int row = c >> 3, sp = c & 7;
            GL_LDS16(Bt + (size_t)(bx * BN + row) * K + kt + SWZ8(row, sp),
                     (char*)sB + c * 16);
        }
        __syncthreads();

        bf16x8 af[4][2], bfr[NJ][2];
#pragma unroll
        for (int i = 0; i < 4; ++i) {
            int row = wr * 64 + i * 16 + l15;
#pragma unroll
            for (int kh = 0; kh < 2; ++kh) {
                int s = kh * 4 + g;
                af[i][kh] = *(const bf16x8*)(&sA[row * 64 + SWZ8(row, s)]);
            }
        }
#pragma unroll
        for (int j = 0; j < NJ; ++j) {
            int row = wc * (BN / 2) + j * 16 + l15;
#pragma unroll
            for (int kh = 0; kh < 2; ++kh) {
                int s = kh * 4 + g;
                bfr[j][kh] = *(const bf16x8*)(&sB[row * 64 + SWZ8(row, s)]);
            }
        }
#pragma unroll
        for (int kh = 0; kh < 2; ++kh)
#pragma unroll
            for (int i = 0; i < 4; ++i)
#pragma unroll
                for (int j = 0; j < NJ; ++j)
                    acc[i][j] = __builtin_amdgcn_mfma_f32_16x16x32_bf16(af[i][kh], bfr[j][kh], acc[i][j], 0, 0, 0);
    }

    if constexpr (TRC && BN == 128) {
        if (z == 2) {
            // transposed epilogue: C[row][col] -> vT[(b*H+h)*64+e][s]
            __syncthreads();   // all waves done reading sA/sB
            short* sT = smem;  // 16384 shorts = full 128x128 bf16 tile
#pragma unroll
            for (int i = 0; i < 4; ++i)
#pragma unroll
                for (int j = 0; j < NJ; ++j)
#pragma unroll
                    for (int r = 0; r < 4; ++r) {
                        int row = wr * 64 + i * 16 + g * 4 + r;
                        int col = wc * 64 + j * 16 + l15;
                        sT[col * 128 + ((((row >> 3) ^ (col & 7)) << 3) | (row & 7))] =
                            f2bf(acc[i][j][r]);
                    }
            __syncthreads();
            {
                int col = tid >> 1, half = tid & 1;
                int cg = bx * 128 + col;
                int h = cg >> 6, e = cg & 63;
                size_t R = ((size_t)(by >> 3) * HH + h) * 64 + e;
                short* dst = (short*)Cv + R * SS + (size_t)(by & 7) * 128 + half * 64;
#pragma unroll
                for (int m = 0; m < 8; ++m) {
                    int mm = half * 8 + m;
                    bf16x8 ch = *(const bf16x8*)(&sT[col * 128 + ((mm ^ (col & 7)) << 3)]);
                    *(bf16x8*)(dst + m * 8) = ch;
                }
            }
            return;
        }
    }

#pragma unroll
    for (int i = 0; i < 4; ++i)
#pragma unroll
        for (int j = 0; j < NJ; ++j)
#pragma unroll
            for (int r = 0; r < 4; ++r) {
                int row = by * 128 + wr * 64 + i * 16 + g * 4 + r;
                int col = bx * BN + wc * (BN / 2) + j * 16 + l15;
                if constexpr (C_F32)
                    ((float*)Cv)[(size_t)row * DDIM + col] = acc[i][j][r];
                else
                    ((short*)Cv)[(size_t)row * DDIM + col] = f2bf(acc[i][j][r]);
            }
}

// ---------------------------------------------------------------------------
// Flash attention per (b, h, 64-q-rows). 4 waves x 16 q-rows, KV tiles of 64.
// Fixed-offset softmax (m=0, exact by shift-invariance; scores clamped at 60):
// p=exp(s), lane-local l accumulation, ONE cross-lane reduce at end.
// TRV: V pre-transposed [b][h][e][s] staged via global_load_lds like K.
// WOT: first 256 blocks transpose Wo -> wt_o (rides in this dispatch).
// LDS bases computed arithmetically (no pointer arrays -> no addrspacecast
// static initializers, which gfx950 clang rejects).
template<bool TRV, bool WOT>
__global__ __launch_bounds__(256) void attn(const short* __restrict__ q,
                                            const short* __restrict__ k,
                                            const short* __restrict__ v,
                                            const int* __restrict__ vlens,
                                            short* __restrict__ att,
                                            const float* __restrict__ Wo,
                                            short* __restrict__ wt_o) {
    __shared__ short asmem[20480];   // 40 KB: sK dbuf | sV dbuf | sP
    const int tid = threadIdx.x;
    int blk = blockIdx.x;
    if constexpr (WOT) {
        if (blk < 256) {
            transposeW_body(Wo, wt_o, (blk >> 4) * 64, (blk & 15) * 64,
                            (short (*)[72])asmem, tid);
            return;
        }
        blk -= 256;
    }

    const int qt = blk >> 6;
    const int hb = blk & 63;
    const int bb = hb & 3;                 // batch varies fastest
    const int h  = hb >> 2;

    const int lane = tid & 63, wid = tid >> 6;
    const int g = lane >> 4, l15 = lane & 15;
    const int vlen = vlens[bb];
    const int pOff = 16384 + wid * 1024;   // per-wave sP base (offset in asmem)

    const int srow = qt * 64 + wid * 16 + l15;
    const short* qrow = q + ((size_t)(bb * SS + srow)) * DDIM + h * 64;
    bf16x8 qf[2];
    qf[0] = *(const bf16x8*)(qrow + g * 8);
    qf[1] = *(const bf16x8*)(qrow + 32 + g * 8);

    float lsum[4] = {0.f, 0.f, 0.f, 0.f};
    f32x4 oacc[4] = {};

    const int key0 = tid >> 3, key1 = (tid + 256) >> 3, sp = tid & 7;
    const int d0 = (tid & 7) << 3;
    const short* vTb = v + ((size_t)(bb * HH + h) * 64) * SS;

    const int ntiles = (vlen + 63) >> 6;

    // ---- prologue: stage tile 0 into buf 0 (offsets: sK=0, sV=8192) ----
    {
        GL_LDS16(k + ((size_t)(bb * SS + key0)) * DDIM + h * 64 + ((sp ^ (key0 & 7)) << 3),
                 (char*)&asmem[0] + tid * 16);
        GL_LDS16(k + ((size_t)(bb * SS + key1)) * DDIM + h * 64 + ((sp ^ (key1 & 7)) << 3),
                 (char*)&asmem[0] + (tid + 256) * 16);
        if constexpr (TRV) {
            GL_LDS16(vTb + (size_t)key0 * SS + ((sp ^ (key0 & 7)) << 3),
                     (char*)&asmem[8192] + tid * 16);
            GL_LDS16(vTb + (size_t)key1 * SS + ((sp ^ (key1 & 7)) << 3),
                     (char*)&asmem[8192] + (tid + 256) * 16);
        } else {
            bf16x8 v0 = *(const bf16x8*)(v + ((size_t)(bb * SS + key0)) * DDIM + h * 64 + d0);
            bf16x8 v1 = *(const bf16x8*)(v + ((size_t)(bb * SS + key1)) * DDIM + h * 64 + d0);
#pragma unroll
            for (int e = 0; e < 8; ++e) {
                int e0 = d0 + e;
                asmem[8192 + e0 * 64 + (((key0 >> 3) ^ (e0 & 7)) << 3) + (key0 & 7)] = v0[e];
                asmem[8192 + e0 * 64 + (((key1 >> 3) ^ (e0 & 7)) << 3) + (key1 & 7)] = v1[e];
            }
        }
    }
    __syncthreads();

    for (int t = 0; t < ntiles; ++t) {
        const int cur = t & 1, nxt = cur ^ 1;
        const int kOffC = cur * 4096, kOffN = nxt * 4096;
        const int vOffC = 8192 + cur * 4096, vOffN = 8192 + nxt * 4096;
        const int kb = t * 64;
        const bool pre = (t + 1 < ntiles);

        bf16x8 vr0, vr1;
        if (pre) {
            const int kb2 = kb + 64;
            GL_LDS16(k + ((size_t)(bb * SS + kb2 + key0)) * DDIM + h * 64 + ((sp ^ (key0 & 7)) << 3),
                     (char*)&asmem[0] + kOffN * 2 + tid * 16);
            GL_LDS16(k + ((size_t)(bb * SS + kb2 + key1)) * DDIM + h * 64 + ((sp ^ (key1 & 7)) << 3),
                     (char*)&asmem[0] + kOffN * 2 + (tid + 256) * 16);
            if constexpr (TRV) {
                GL_LDS16(vTb + (size_t)key0 * SS + kb2 + ((sp ^ (key0 & 7)) << 3),
                         (char*)&asmem[0] + vOffN * 2 + tid * 16);
                GL_LDS16(vTb + (size_t)key1 * SS + kb2 + ((sp ^ (key1 & 7)) << 3),
                         (char*)&asmem[0] + vOffN * 2 + (tid + 256) * 16);
            } else {
                vr0 = *(const bf16x8*)(v + ((size_t)(bb * SS + kb2 + key0)) * DDIM + h * 64 + d0);
                vr1 = *(const bf16x8*)(v + ((size_t)(bb * SS + kb2 + key1)) * DDIM + h * 64 + d0);
            }
        }

        f32x4 sacc[4] = {};
#pragma unroll
        for (int kg = 0; kg < 4; ++kg) {
            int row = kg * 16 + l15;
#pragma unroll
            for (int kh = 0; kh < 2; ++kh) {
                int s = kh * 4 + g;
                bf16x8 kf = *(const bf16x8*)(&asmem[kOffC + row * 64 + ((s ^ (row & 7)) << 3)]);
                sacc[kg] = __builtin_amdgcn_mfma_f32_16x16x32_bf16(qf[kh], kf, sacc[kg], 0, 0, 0);
            }
        }

#pragma unroll
        for (int r = 0; r < 4; ++r) {
            float p[4], ls = 0.f;
#pragma unroll
            for (int kg = 0; kg < 4; ++kg) {
                float s = fminf(sacc[kg][r] * 0.125f, 60.0f);
                if (kb + kg * 16 + l15 >= vlen) s = -1e30f;
                p[kg] = __expf(s);
                ls += p[kg];
            }
            lsum[r] += ls;
            const int srw = g * 4 + r;
#pragma unroll
            for (int kg = 0; kg < 4; ++kg) {
                int col = kg * 16 + l15;
                asmem[pOff + srw * 64 + (((col >> 3) ^ (srw & 7)) << 3) + (col & 7)] = f2bf(p[kg]);
            }
        }

        bf16x8 pf[2];
#pragma unroll
        for (int kh = 0; kh < 2; ++kh) {
            int s = kh * 4 + g;
            pf[kh] = *(const bf16x8*)(&asmem[pOff + l15 * 64 + ((s ^ (l15 & 7)) << 3)]);
        }
#pragma unroll
        for (int n = 0; n < 4; ++n) {
            const int e = n * 16 + l15;
#pragma unroll
            for (int kh = 0; kh < 2; ++kh) {
                int s = kh * 4 + g;
                bf16x8 vf = *(const bf16x8*)(&asmem[vOffC + e * 64 + ((s ^ (e & 7)) << 3)]);
                oacc[n] = __builtin_amdgcn_mfma_f32_16x16x32_bf16(pf[kh], vf, oacc[n], 0, 0, 0);
            }
        }

        if constexpr (!TRV) {
            if (pre) {
#pragma unroll
                for (int e = 0; e < 8; ++e) {
                    int e0 = d0 + e;
                    asmem[vOffN + e0 * 64 + (((key0 >> 3) ^ (e0 & 7)) << 3) + (key0 & 7)] = vr0[e];
                    asmem[vOffN + e0 * 64 + (((key1 >> 3) ^ (e0 & 7)) << 3) + (key1 & 7)] = vr1[e];
                }
            }
        }
        __syncthreads();
    }

#pragma unroll
    for (int r = 0; r < 4; ++r) {
        float rs = lsum[r];
#pragma unroll
        for (int off = 1; off < 16; off <<= 1)
            rs += __shfl_xor(rs, off);
        lsum[r] = rs;
    }

#pragma unroll
    for (int n = 0; n < 4; ++n)
#pragma unroll
        for (int r = 0; r < 4; ++r) {
            float o = oacc[n][r] / lsum[r];
            int sg = qt * 64 + wid * 16 + g * 4 + r;
            int e = n * 16 + l15;
            att[((size_t)(bb * SS + sg)) * DDIM + e * HH + h] = f2bf(o);
        }
}

extern "C" void kernel_launch(void* const* d_in, const int* in_sizes, int n_in,
                              void* d_out, int out_size, void* d_ws, size_t ws_size,
                              hipStream_t stream) {
    const float* queries = (const float*)d_in[0];
    const float* keys    = (const float*)d_in[1];
    const float* values  = (const float*)d_in[2];
    const int*   vlens   = (const int*)d_in[3];
    const float* Wq      = (const float*)d_in[4];
    const float* Wk      = (const float*)d_in[5];
    const float* Wv      = (const float*)d_in[6];
    const float* Wo      = (const float*)d_in[7];
    float* out = (float*)d_out;

    short* ws = (short*)d_ws;
    const size_t sz = (size_t)MROWS * DDIM;   // 4M elems, 8MB per region
    short* q_ws   = ws;
    short* k_ws   = ws + sz;
    short* reg2   = ws + 2 * sz;              // big: vT; mid/small: v_ws
    short* att_ws = ws + 3 * sz;
    short* wt3    = att_ws;                   // dead until attn writes

    const size_t regionB = sz * sizeof(short);
    const bool big = ws_size >= 7 * regionB;
    const bool mid = ws_size >= 5 * regionB;

    if (big) {
        short* qb = ws + 4 * sz;              // cvt Q
        short* kb = ws + 5 * sz;              // cvt K
        short* vb = ws + 6 * sz;              // cvt V; later wt_o
        // prep: cvt QKV (6144 blocks) + transpose Wq/Wk/Wv (768 blocks)
        prep<<<dim3(6912), 256, 0, stream>>>(queries, keys, values,
                                             Wq, Wk, Wv, qb, wt3, vlens);
        // QKV projections; z==2 writes V output directly transposed into vT
        gemm<false, false, 128, true, true><<<dim3(768), 256, 0, stream>>>(
            qb, kb, vb, wt3, q_ws, k_ws, reg2, vlens);
        // attn (1024 blocks) + Wo transpose into vb (256 blocks, first)
        attn<true, true><<<dim3(1280), 256, 0, stream>>>(
            q_ws, k_ws, reg2, vlens, att_ws, Wo, vb);
        gemm<false, true, 64, false, false><<<dim3(512), 256, 0, stream>>>(
            att_ws, att_ws, att_ws, vb, out, out, out, vlens);
    } else if (mid) {
        short* vT = ws + 4 * sz;
        short* wt_o = q_ws;                   // dead after attn reads q
        transposeW3<<<dim3(16, 16, 3), 256, 0, stream>>>(Wq, Wk, Wv, wt3);
        gemm<true, false, 128, true, false><<<dim3(768), 256, 0, stream>>>(
            queries, keys, values, wt3, q_ws, k_ws, reg2, vlens);
        transposeV<<<dim3(16, 16, 4), 256, 0, stream>>>(reg2, vT, vlens);
        attn<true, false><<<dim3(1024), 256, 0, stream>>>(
            q_ws, k_ws, vT, vlens, att_ws, Wo, wt_o);
        transposeW3<<<dim3(16, 16, 1), 256, 0, stream>>>(Wo, Wo, Wo, wt_o);
        gemm<false, true, 64, false, false><<<dim3(512), 256, 0, stream>>>(
            att_ws, att_ws, att_ws, wt_o, out, out, out, vlens);
    } else {
        short* wt_o = q_ws;
        transposeW3<<<dim3(16, 16, 3), 256, 0, stream>>>(Wq, Wk, Wv, wt3);
        gemm<true, false, 128, true, false><<<dim3(768), 256, 0, stream>>>(
            queries, keys, values, wt3, q_ws, k_ws, reg2, vlens);
        attn<false, false><<<dim3(1024), 256, 0, stream>>>(
            q_ws, k_ws, reg2, vlens, att_ws, Wo, wt_o);
        transposeW3<<<dim3(16, 16, 1), 256, 0, stream>>>(Wo, Wo, Wo, wt_o);
        gemm<false, true, 64, false, false><<<dim3(512), 256, 0, stream>>>(
            att_ws, att_ws, att_ws, wt_o, out, out, out, vlens);
    }
}

// Round 16
// 89.021 us; speedup vs baseline: 1.6778x; 1.0211x over previous
//
#include <hip/hip_runtime.h>
#include <hip/hip_bf16.h>

#define BB 4
#define SS 1024
#define DDIM 1024
#define HH 16
#define MROWS (BB * SS)

typedef __attribute__((ext_vector_type(8))) short bf16x8;
typedef __attribute__((ext_vector_type(4))) float f32x4;

static __device__ __forceinline__ short f2bf(float x) {
    union { __hip_bfloat16 h; short s; } u;
    u.h = __float2bfloat16(x);
    return u.s;
}

#define GL_LDS16(gp, lp)                                                      \
    __builtin_amdgcn_global_load_lds(                                         \
        (const __attribute__((address_space(1))) void*)(gp),                  \
        (__attribute__((address_space(3))) void*)(lp), 16, 0, 0)

// 128B-row swizzle (8 x 16B slots): physical slot = s ^ (row&7).
#define SWZ8(row, s) (((s) ^ ((row) & 7)) << 3)

// ---------------------------------------------------------------------------
// Shared transpose helper body: W [K,N] f32 64x64 tile -> dst [N,K] bf16.
static __device__ __forceinline__ void transposeW_body(const float* __restrict__ W,
                                                       short* __restrict__ dst,
                                                       int k0, int n0,
                                                       short (*sT)[72], int t) {
    {
        int r = t >> 2, cq = (t & 3) << 4;
        const float* p = W + (size_t)(k0 + r) * DDIM + n0 + cq;
        float4 a = ((const float4*)p)[0], b = ((const float4*)p)[1];
        float4 c = ((const float4*)p)[2], d = ((const float4*)p)[3];
        short* dp = &sT[r][cq];
        dp[0]  = f2bf(a.x); dp[1]  = f2bf(a.y); dp[2]  = f2bf(a.z); dp[3]  = f2bf(a.w);
        dp[4]  = f2bf(b.x); dp[5]  = f2bf(b.y); dp[6]  = f2bf(b.z); dp[7]  = f2bf(b.w);
        dp[8]  = f2bf(c.x); dp[9]  = f2bf(c.y); dp[10] = f2bf(c.z); dp[11] = f2bf(c.w);
        dp[12] = f2bf(d.x); dp[13] = f2bf(d.y); dp[14] = f2bf(d.z); dp[15] = f2bf(d.w);
    }
    __syncthreads();
    {
        int n = t >> 2, kq = (t & 3) << 4;
        bf16x8 o0, o1;
#pragma unroll
        for (int j = 0; j < 8; ++j) o0[j] = sT[kq + j][n];
#pragma unroll
        for (int j = 0; j < 8; ++j) o1[j] = sT[kq + 8 + j][n];
        short* q = dst + (size_t)(n0 + n) * DDIM + k0 + kq;
        *(bf16x8*)q = o0;
        *(bf16x8*)(q + 8) = o1;
    }
}

// ---------------------------------------------------------------------------
// PREP (merged): blocks [0,768): transposeW of Wq/Wk/Wv (FIRST, so their
// 2-phase LDS latency overlaps the cvt stream). Blocks [768,6912): f32->bf16
// cvt of Q/K/V activations (vlen-skipped for K/V).
__global__ __launch_bounds__(256) void prep(const float* __restrict__ X0,
                                            const float* __restrict__ X1,
                                            const float* __restrict__ X2,
                                            const float* __restrict__ W0,
                                            const float* __restrict__ W1,
                                            const float* __restrict__ W2,
                                            short* __restrict__ dstA,
                                            short* __restrict__ Wt,
                                            const int* __restrict__ vlens) {
    __shared__ short sT[64][72];
    const int bx = blockIdx.x;
    const int t = threadIdx.x;
    if (bx < 768) {
        const int z = bx >> 8;
        const int rem = bx & 255;
        const float* W = (z == 0) ? W0 : (z == 1) ? W1 : W2;
        transposeW_body(W, Wt + (size_t)z * DDIM * DDIM,
                        (rem >> 4) * 64, (rem & 15) * 64, sT, t);
        return;
    }
    const int bc = bx - 768;
    const int z = bc >> 11;
    const int blk = bc & 2047;
    const int row0 = blk << 1;
    if (z >= 1) {
        const int bb = row0 >> 10;
        if ((row0 & 1023) >= vlens[bb]) return;
    }
    const float* X = (z == 0) ? X0 : (z == 1) ? X1 : X2;
    short* D = dstA + (size_t)z * MROWS * DDIM;
    const size_t base = (size_t)blk * 2048 + t * 8;
    const float4 x0 = ((const float4*)(X + base))[0];
    const float4 x1 = ((const float4*)(X + base))[1];
    bf16x8 vv;
    vv[0] = f2bf(x0.x); vv[1] = f2bf(x0.y); vv[2] = f2bf(x0.z); vv[3] = f2bf(x0.w);
    vv[4] = f2bf(x1.x); vv[5] = f2bf(x1.y); vv[6] = f2bf(x1.z); vv[7] = f2bf(x1.w);
    *(bf16x8*)(D + base) = vv;
}

// ---------------------------------------------------------------------------
// Fallback standalone kernels (mid/small-ws paths).
__global__ __launch_bounds__(256) void transposeW3(const float* __restrict__ W0,
                                                   const float* __restrict__ W1,
                                                   const float* __restrict__ W2,
                                                   short* __restrict__ Wt) {
    __shared__ short sT[64][72];
    const int z = blockIdx.z;
    const float* W = (z == 0) ? W0 : (z == 1) ? W1 : W2;
    transposeW_body(W, Wt + (size_t)z * DDIM * DDIM,
                    blockIdx.y * 64, blockIdx.x * 64, sT, threadIdx.x);
}

__global__ __launch_bounds__(256) void transposeV(const short* __restrict__ v,
                                                  short* __restrict__ vT,
                                                  const int* __restrict__ vlens) {
    const int st = blockIdx.x, h = blockIdx.y, bb = blockIdx.z;
    if (st * 64 >= vlens[bb]) return;
    __shared__ short sT[64][72];
    const int t = threadIdx.x;
#pragma unroll
    for (int j = 0; j < 2; ++j) {
        int c = t + j * 256;
        int sr = c >> 3, co = (c & 7) << 3;
        *(bf16x8*)(&sT[sr][co]) =
            *(const bf16x8*)(v + (size_t)(bb * SS + st * 64 + sr) * DDIM + h * 64 + co);
    }
    __syncthreads();
    {
        int e = t >> 2, sq = (t & 3) << 4;
        bf16x8 o0, o1;
#pragma unroll
        for (int j = 0; j < 8; ++j) o0[j] = sT[sq + j][e];
#pragma unroll
        for (int j = 0; j < 8; ++j) o1[j] = sT[sq + 8 + j][e];
        short* dst = vT + ((size_t)(bb * HH + h) * 64 + e) * SS + st * 64 + sq;
        *(bf16x8*)dst = o0;
        *(bf16x8*)(dst + 8) = o1;
    }
}

// ---------------------------------------------------------------------------
// C[z][M,N] = A[z][M,K] @ Bt[z][N,K]^T, up to 3 fused problems.
// m97 structure: BM=128, BN template, BK=64, single LDS buffer, 2 barriers
// per K-step, 32 MFMA/wave/step, global_load_lds staging, SWZ8 both sides.
// Batch-balanced XCD mapping: by = k4*8 + ((xcd+2*k4)&7) spreads each
// batch's row panels across ALL XCDs so vlen-SKIP is load-balanced
// (same-by blocks still share one XCD -> A-panel L2 reuse kept).
// TRC (BN=128 only): z==2 writes C TRANSPOSED to vT[b][h][e][s].
template<bool A_F32, bool C_F32, int BN, bool SKIP, bool TRC>
__global__ __launch_bounds__(256) void gemm(const void* __restrict__ A0v,
                                            const void* __restrict__ A1v,
                                            const void* __restrict__ A2v,
                                            const short* __restrict__ BtBase,
                                            void* __restrict__ C0v,
                                            void* __restrict__ C1v,
                                            void* __restrict__ C2v,
                                            const int* __restrict__ vlens) {
    constexpr int NJ  = BN / 32;
    constexpr int NBX = DDIM / BN;
    constexpr int NPB = 32 * NBX;
    constexpr int BCH = BN / 32;

    __shared__ short smem[128 * 64 + BN * 64];
    short* sA = smem;
    short* sB = smem + 128 * 64;

    const int tid = threadIdx.x;
    const int lane = tid & 63, wid = tid >> 6;
    const int wr = wid >> 1, wc = wid & 1;
    const int g = lane >> 4, l15 = lane & 15;

    const int blk = blockIdx.x;
    const int z = blk / NPB;
    const int inner = blk % NPB;
    const int xcd = inner & 7, ii = inner >> 3;
    const int k4 = ii / NBX;                       // row-group == batch
    const int by = k4 * 8 + ((xcd + 2 * k4) & 7);  // balanced panel rotation
    const int bx = ii % NBX;

    if constexpr (SKIP) {
        if (z >= 1 && ((by & 7) << 7) >= vlens[by >> 3]) return;
    }

    const void* Av = (z == 0) ? A0v : (z == 1) ? A1v : A2v;
    const short* Bt = BtBase + (size_t)z * DDIM * DDIM;
    void* Cv = (z == 0) ? C0v : (z == 1) ? C1v : C2v;
    const float* Af = (const float*)Av;
    const short* Ab = (const short*)Av;
    const int K = DDIM;

    f32x4 acc[4][NJ] = {};
    const int nkt = K >> 6;

    for (int t = 0; t < nkt; ++t) {
        const int kt = t << 6;
        __syncthreads();

        if constexpr (A_F32) {
            float4 ra[4][2];
#pragma unroll
            for (int j = 0; j < 4; ++j) {
                int c = tid + j * 256;
                int row = c >> 3, s = c & 7;
                const float* p = Af + (size_t)(by * 128 + row) * K + kt + s * 8;
                ra[j][0] = ((const float4*)p)[0];
                ra[j][1] = ((const float4*)p)[1];
            }
#pragma unroll
            for (int j = 0; j < 4; ++j) {
                int c = tid + j * 256;
                int row = c >> 3, s = c & 7;
                bf16x8 vv;
                vv[0] = f2bf(ra[j][0].x); vv[1] = f2bf(ra[j][0].y);
                vv[2] = f2bf(ra[j][0].z); vv[3] = f2bf(ra[j][0].w);
                vv[4] = f2bf(ra[j][1].x); vv[5] = f2bf(ra[j][1].y);
                vv[6] = f2bf(ra[j][1].z); vv[7] = f2bf(ra[j][1].w);
                *(bf16x8*)(&sA[row * 64 + SWZ8(row, s)]) = vv;
            }
        } else {
#pragma unroll
            for (int j = 0; j < 4; ++j) {
                int c = tid + j * 256;
                int row = c >> 3, sp = c & 7;
                GL_LDS16(Ab + (size_t)(by * 128 + row) * K + kt + SWZ8(row, sp),
                         (char*)sA + c * 16);
            }
        }
#pragma unroll
        for (int j = 0; j < BCH; ++j) {
            int c = tid + j * 256;
            int row = c >> 3, sp = c & 7;
            GL_LDS16(Bt + (size_t)(bx * BN + row) * K + kt + SWZ8(row, sp),
                     (char*)sB + c * 16);
        }
        __syncthreads();

        bf16x8 af[4][2], bfr[NJ][2];
#pragma unroll
        for (int i = 0; i < 4; ++i) {
            int row = wr * 64 + i * 16 + l15;
#pragma unroll
            for (int kh = 0; kh < 2; ++kh) {
                int s = kh * 4 + g;
                af[i][kh] = *(const bf16x8*)(&sA[row * 64 + SWZ8(row, s)]);
            }
        }
#pragma unroll
        for (int j = 0; j < NJ; ++j) {
            int row = wc * (BN / 2) + j * 16 + l15;
#pragma unroll
            for (int kh = 0; kh < 2; ++kh) {
                int s = kh * 4 + g;
                bfr[j][kh] = *(const bf16x8*)(&sB[row * 64 + SWZ8(row, s)]);
            }
        }
#pragma unroll
        for (int kh = 0; kh < 2; ++kh)
#pragma unroll
            for (int i = 0; i < 4; ++i)
#pragma unroll
                for (int j = 0; j < NJ; ++j)
                    acc[i][j] = __builtin_amdgcn_mfma_f32_16x16x32_bf16(af[i][kh], bfr[j][kh], acc[i][j], 0, 0, 0);
    }

    if constexpr (TRC && BN == 128) {
        if (z == 2) {
            // transposed epilogue: C[row][col] -> vT[(b*H+h)*64+e][s]
            __syncthreads();   // all waves done reading sA/sB
            short* sT = smem;  // 16384 shorts = full 128x128 bf16 tile
#pragma unroll
            for (int i = 0; i < 4; ++i)
#pragma unroll
                for (int j = 0; j < NJ; ++j)
#pragma unroll
                    for (int r = 0; r < 4; ++r) {
                        int row = wr * 64 + i * 16 + g * 4 + r;
                        int col = wc * 64 + j * 16 + l15;
                        sT[col * 128 + ((((row >> 3) ^ (col & 7)) << 3) | (row & 7))] =
                            f2bf(acc[i][j][r]);
                    }
            __syncthreads();
            {
                int col = tid >> 1, half = tid & 1;
                int cg = bx * 128 + col;
                int h = cg >> 6, e = cg & 63;
                size_t R = ((size_t)(by >> 3) * HH + h) * 64 + e;
                short* dst = (short*)Cv + R * SS + (size_t)(by & 7) * 128 + half * 64;
#pragma unroll
                for (int m = 0; m < 8; ++m) {
                    int mm = half * 8 + m;
                    bf16x8 ch = *(const bf16x8*)(&sT[col * 128 + ((mm ^ (col & 7)) << 3)]);
                    *(bf16x8*)(dst + m * 8) = ch;
                }
            }
            return;
        }
    }

#pragma unroll
    for (int i = 0; i < 4; ++i)
#pragma unroll
        for (int j = 0; j < NJ; ++j)
#pragma unroll
            for (int r = 0; r < 4; ++r) {
                int row = by * 128 + wr * 64 + i * 16 + g * 4 + r;
                int col = bx * BN + wc * (BN / 2) + j * 16 + l15;
                if constexpr (C_F32)
                    ((float*)Cv)[(size_t)row * DDIM + col] = acc[i][j][r];
                else
                    ((short*)Cv)[(size_t)row * DDIM + col] = f2bf(acc[i][j][r]);
            }
}

// ---------------------------------------------------------------------------
// Flash attention per (b, h, 64-q-rows). 4 waves x 16 q-rows, KV tiles of 64.
// Fixed-offset softmax (m=0, exact by shift-invariance; scores clamped at 60):
// p=exp(s), lane-local l accumulation, ONE cross-lane reduce at end.
// TRV: V pre-transposed [b][h][e][s] staged via global_load_lds like K.
// WOT: first 256 blocks transpose Wo -> wt_o (rides in this dispatch).
template<bool TRV, bool WOT>
__global__ __launch_bounds__(256) void attn(const short* __restrict__ q,
                                            const short* __restrict__ k,
                                            const short* __restrict__ v,
                                            const int* __restrict__ vlens,
                                            short* __restrict__ att,
                                            const float* __restrict__ Wo,
                                            short* __restrict__ wt_o) {
    __shared__ short asmem[20480];   // 40 KB: sK dbuf | sV dbuf | sP
    const int tid = threadIdx.x;
    int blk = blockIdx.x;
    if constexpr (WOT) {
        if (blk < 256) {
            transposeW_body(Wo, wt_o, (blk >> 4) * 64, (blk & 15) * 64,
                            (short (*)[72])asmem, tid);
            return;
        }
        blk -= 256;
    }

    const int qt = blk >> 6;
    const int hb = blk & 63;
    const int bb = hb & 3;                 // batch varies fastest
    const int h  = hb >> 2;

    const int lane = tid & 63, wid = tid >> 6;
    const int g = lane >> 4, l15 = lane & 15;
    const int vlen = vlens[bb];
    const int pOff = 16384 + wid * 1024;   // per-wave sP base (offset in asmem)

    const int srow = qt * 64 + wid * 16 + l15;
    const short* qrow = q + ((size_t)(bb * SS + srow)) * DDIM + h * 64;
    bf16x8 qf[2];
    qf[0] = *(const bf16x8*)(qrow + g * 8);
    qf[1] = *(const bf16x8*)(qrow + 32 + g * 8);

    float lsum[4] = {0.f, 0.f, 0.f, 0.f};
    f32x4 oacc[4] = {};

    const int key0 = tid >> 3, key1 = (tid + 256) >> 3, sp = tid & 7;
    const int d0 = (tid & 7) << 3;
    const short* vTb = v + ((size_t)(bb * HH + h) * 64) * SS;

    const int ntiles = (vlen + 63) >> 6;

    // ---- prologue: stage tile 0 into buf 0 (offsets: sK=0, sV=8192) ----
    {
        GL_LDS16(k + ((size_t)(bb * SS + key0)) * DDIM + h * 64 + ((sp ^ (key0 & 7)) << 3),
                 (char*)&asmem[0] + tid * 16);
        GL_LDS16(k + ((size_t)(bb * SS + key1)) * DDIM + h * 64 + ((sp ^ (key1 & 7)) << 3),
                 (char*)&asmem[0] + (tid + 256) * 16);
        if constexpr (TRV) {
            GL_LDS16(vTb + (size_t)key0 * SS + ((sp ^ (key0 & 7)) << 3),
                     (char*)&asmem[8192] + tid * 16);
            GL_LDS16(vTb + (size_t)key1 * SS + ((sp ^ (key1 & 7)) << 3),
                     (char*)&asmem[8192] + (tid + 256) * 16);
        } else {
            bf16x8 v0 = *(const bf16x8*)(v + ((size_t)(bb * SS + key0)) * DDIM + h * 64 + d0);
            bf16x8 v1 = *(const bf16x8*)(v + ((size_t)(bb * SS + key1)) * DDIM + h * 64 + d0);
#pragma unroll
            for (int e = 0; e < 8; ++e) {
                int e0 = d0 + e;
                asmem[8192 + e0 * 64 + (((key0 >> 3) ^ (e0 & 7)) << 3) + (key0 & 7)] = v0[e];
                asmem[8192 + e0 * 64 + (((key1 >> 3) ^ (e0 & 7)) << 3) + (key1 & 7)] = v1[e];
            }
        }
    }
    __syncthreads();

    for (int t = 0; t < ntiles; ++t) {
        const int cur = t & 1, nxt = cur ^ 1;
        const int kOffC = cur * 4096, kOffN = nxt * 4096;
        const int vOffC = 8192 + cur * 4096, vOffN = 8192 + nxt * 4096;
        const int kb = t * 64;
        const bool pre = (t + 1 < ntiles);

        bf16x8 vr0, vr1;
        if (pre) {
            const int kb2 = kb + 64;
            GL_LDS16(k + ((size_t)(bb * SS + kb2 + key0)) * DDIM + h * 64 + ((sp ^ (key0 & 7)) << 3),
                     (char*)&asmem[0] + kOffN * 2 + tid * 16);
            GL_LDS16(k + ((size_t)(bb * SS + kb2 + key1)) * DDIM + h * 64 + ((sp ^ (key1 & 7)) << 3),
                     (char*)&asmem[0] + kOffN * 2 + (tid + 256) * 16);
            if constexpr (TRV) {
                GL_LDS16(vTb + (size_t)key0 * SS + kb2 + ((sp ^ (key0 & 7)) << 3),
                         (char*)&asmem[0] + vOffN * 2 + tid * 16);
                GL_LDS16(vTb + (size_t)key1 * SS + kb2 + ((sp ^ (key1 & 7)) << 3),
                         (char*)&asmem[0] + vOffN * 2 + (tid + 256) * 16);
            } else {
                vr0 = *(const bf16x8*)(v + ((size_t)(bb * SS + kb2 + key0)) * DDIM + h * 64 + d0);
                vr1 = *(const bf16x8*)(v + ((size_t)(bb * SS + kb2 + key1)) * DDIM + h * 64 + d0);
            }
        }

        f32x4 sacc[4] = {};
#pragma unroll
        for (int kg = 0; kg < 4; ++kg) {
            int row = kg * 16 + l15;
#pragma unroll
            for (int kh = 0; kh < 2; ++kh) {
                int s = kh * 4 + g;
                bf16x8 kf = *(const bf16x8*)(&asmem[kOffC + row * 64 + ((s ^ (row & 7)) << 3)]);
                sacc[kg] = __builtin_amdgcn_mfma_f32_16x16x32_bf16(qf[kh], kf, sacc[kg], 0, 0, 0);
            }
        }

#pragma unroll
        for (int r = 0; r < 4; ++r) {
            float p[4], ls = 0.f;
#pragma unroll
            for (int kg = 0; kg < 4; ++kg) {
                float s = fminf(sacc[kg][r] * 0.125f, 60.0f);
                if (kb + kg * 16 + l15 >= vlen) s = -1e30f;
                p[kg] = __expf(s);
                ls += p[kg];
            }
            lsum[r] += ls;
            const int srw = g * 4 + r;
#pragma unroll
            for (int kg = 0; kg < 4; ++kg) {
                int col = kg * 16 + l15;
                asmem[pOff + srw * 64 + (((col >> 3) ^ (srw & 7)) << 3) + (col & 7)] = f2bf(p[kg]);
            }
        }

        bf16x8 pf[2];
#pragma unroll
        for (int kh = 0; kh < 2; ++kh) {
            int s = kh * 4 + g;
            pf[kh] = *(const bf16x8*)(&asmem[pOff + l15 * 64 + ((s ^ (l15 & 7)) << 3)]);
        }
#pragma unroll
        for (int n = 0; n < 4; ++n) {
            const int e = n * 16 + l15;
#pragma unroll
            for (int kh = 0; kh < 2; ++kh) {
                int s = kh * 4 + g;
                bf16x8 vf = *(const bf16x8*)(&asmem[vOffC + e * 64 + ((s ^ (e & 7)) << 3)]);
                oacc[n] = __builtin_amdgcn_mfma_f32_16x16x32_bf16(pf[kh], vf, oacc[n], 0, 0, 0);
            }
        }

        if constexpr (!TRV) {
            if (pre) {
#pragma unroll
                for (int e = 0; e < 8; ++e) {
                    int e0 = d0 + e;
                    asmem[vOffN + e0 * 64 + (((key0 >> 3) ^ (e0 & 7)) << 3) + (key0 & 7)] = vr0[e];
                    asmem[vOffN + e0 * 64 + (((key1 >> 3) ^ (e0 & 7)) << 3) + (key1 & 7)] = vr1[e];
                }
            }
        }
        __syncthreads();
    }

#pragma unroll
    for (int r = 0; r < 4; ++r) {
        float rs = lsum[r];
#pragma unroll
        for (int off = 1; off < 16; off <<= 1)
            rs += __shfl_xor(rs, off);
        lsum[r] = rs;
    }

#pragma unroll
    for (int n = 0; n < 4; ++n)
#pragma unroll
        for (int r = 0; r < 4; ++r) {
            float o = oacc[n][r] / lsum[r];
            int sg = qt * 64 + wid * 16 + g * 4 + r;
            int e = n * 16 + l15;
            att[((size_t)(bb * SS + sg)) * DDIM + e * HH + h] = f2bf(o);
        }
}

extern "C" void kernel_launch(void* const* d_in, const int* in_sizes, int n_in,
                              void* d_out, int out_size, void* d_ws, size_t ws_size,
                              hipStream_t stream) {
    const float* queries = (const float*)d_in[0];
    const float* keys    = (const float*)d_in[1];
    const float* values  = (const float*)d_in[2];
    const int*   vlens   = (const int*)d_in[3];
    const float* Wq      = (const float*)d_in[4];
    const float* Wk      = (const float*)d_in[5];
    const float* Wv      = (const float*)d_in[6];
    const float* Wo      = (const float*)d_in[7];
    float* out = (float*)d_out;

    short* ws = (short*)d_ws;
    const size_t sz = (size_t)MROWS * DDIM;   // 4M elems, 8MB per region
    short* q_ws   = ws;
    short* k_ws   = ws + sz;
    short* reg2   = ws + 2 * sz;              // big: vT; mid/small: v_ws
    short* att_ws = ws + 3 * sz;
    short* wt3    = att_ws;                   // dead until attn writes

    const size_t regionB = sz * sizeof(short);
    const bool big = ws_size >= 7 * regionB;
    const bool mid = ws_size >= 5 * regionB;

    if (big) {
        short* qb = ws + 4 * sz;              // cvt Q
        short* kb = ws + 5 * sz;              // cvt K
        short* vb = ws + 6 * sz;              // cvt V; later wt_o
        // prep: transpose Wq/Wk/Wv (768 blocks, first) + cvt QKV (6144 blocks)
        prep<<<dim3(6912), 256, 0, stream>>>(queries, keys, values,
                                             Wq, Wk, Wv, qb, wt3, vlens);
        // QKV projections; z==2 writes V output directly transposed into vT
        gemm<false, false, 128, true, true><<<dim3(768), 256, 0, stream>>>(
            qb, kb, vb, wt3, q_ws, k_ws, reg2, vlens);
        // attn (1024 blocks) + Wo transpose into vb (256 blocks, first)
        attn<true, true><<<dim3(1280), 256, 0, stream>>>(
            q_ws, k_ws, reg2, vlens, att_ws, Wo, vb);
        gemm<false, true, 64, false, false><<<dim3(512), 256, 0, stream>>>(
            att_ws, att_ws, att_ws, vb, out, out, out, vlens);
    } else if (mid) {
        short* vT = ws + 4 * sz;
        short* wt_o = q_ws;                   // dead after attn reads q
        transposeW3<<<dim3(16, 16, 3), 256, 0, stream>>>(Wq, Wk, Wv, wt3);
        gemm<true, false, 128, true, false><<<dim3(768), 256, 0, stream>>>(
            queries, keys, values, wt3, q_ws, k_ws, reg2, vlens);
        transposeV<<<dim3(16, 16, 4), 256, 0, stream>>>(reg2, vT, vlens);
        attn<true, false><<<dim3(1024), 256, 0, stream>>>(
            q_ws, k_ws, vT, vlens, att_ws, Wo, wt_o);
        transposeW3<<<dim3(16, 16, 1), 256, 0, stream>>>(Wo, Wo, Wo, wt_o);
        gemm<false, true, 64, false, false><<<dim3(512), 256, 0, stream>>>(
            att_ws, att_ws, att_ws, wt_o, out, out, out, vlens);
    } else {
        short* wt_o = q_ws;
        transposeW3<<<dim3(16, 16, 3), 256, 0, stream>>>(Wq, Wk, Wv, wt3);
        gemm<true, false, 128, true, false><<<dim3(768), 256, 0, stream>>>(
            queries, keys, values, wt3, q_ws, k_ws, reg2, vlens);
        attn<false, false><<<dim3(1024), 256, 0, stream>>>(
            q_ws, k_ws, reg2, vlens, att_ws, Wo, wt_o);
        transposeW3<<<dim3(16, 16, 1), 256, 0, stream>>>(Wo, Wo, Wo, wt_o);
        gemm<false, true, 64, false, false><<<dim3(512), 256, 0, stream>>>(
            att_ws, att_ws, att_ws, wt_o, out, out, out, vlens);
    }
}